// Round 5
// baseline (822.442 us; speedup 1.0000x reference)
//
#include <hip/hip_runtime.h>
#include <hip/hip_bf16.h>
#include <math.h>

// Problem constants (fixed-size problem)
#define NN      200000   // nodes
#define EE      600000   // directed edges
#define GG      8192     // graphs
#define DIN     64       // input dim
#define HD      128      // hidden dim
#define NL      4        // layers
#define LN_EPS  1e-5f

static constexpr int NB_SCAN = (NN + 255) / 256;   // 782 blocks for node scan

typedef __attribute__((ext_vector_type(8))) short short8;   // 8 bf16 (4 VGPRs)
typedef __attribute__((ext_vector_type(4))) float floatx4;  // MFMA accumulator

// bf16x2 <-> float2 (exact: bf16->f32 is a 16-bit shift)
__device__ inline float2 unpack_bf2(unsigned int p) {
    return make_float2(__uint_as_float(p << 16), __uint_as_float(p & 0xffff0000u));
}
__device__ inline unsigned int pack_bf2(float a, float b) {
    __hip_bfloat16 lo = __float2bfloat16(a);
    __hip_bfloat16 hi = __float2bfloat16(b);
    unsigned short ul = *reinterpret_cast<unsigned short*>(&lo);
    unsigned short uh = *reinterpret_cast<unsigned short*>(&hi);
    return (unsigned int)ul | ((unsigned int)uh << 16);
}
__device__ inline short bf16bits(float x) {
    __hip_bfloat16 t = __float2bfloat16(x);
    return *reinterpret_cast<short*>(&t);
}

// ---------------------------------------------------------------------------
// CSR build: degree histogram -> exclusive scan -> edge fill (with edge norm)
// ---------------------------------------------------------------------------
__global__ void hist_kernel(const int* __restrict__ dst, int* __restrict__ degi) {
    int e = blockIdx.x * 256 + threadIdx.x;
    if (e < EE) atomicAdd(&degi[dst[e]], 1);
}

__global__ void dis_kernel(const int* __restrict__ degi, float* __restrict__ dis) {
    int n = blockIdx.x * 256 + threadIdx.x;
    if (n < NN) dis[n] = rsqrtf((float)degi[n] + 1.0f);
}

__global__ void scan1_kernel(const int* __restrict__ degi, int* __restrict__ offs,
                             int* __restrict__ bsums) {
    __shared__ int s[256];
    int t = threadIdx.x;
    int i = blockIdx.x * 256 + t;
    int v = (i < NN) ? degi[i] : 0;
    s[t] = v;
    __syncthreads();
    for (int d = 1; d < 256; d <<= 1) {
        int add = (t >= d) ? s[t - d] : 0;
        __syncthreads();
        s[t] += add;
        __syncthreads();
    }
    if (i < NN) offs[i] = s[t] - v;
    if (t == 255) bsums[blockIdx.x] = s[255];
}

__global__ void scan2_kernel(int* __restrict__ bsums) {
    __shared__ int s[1024];
    int t = threadIdx.x;
    int v = (t < NB_SCAN) ? bsums[t] : 0;
    s[t] = v;
    __syncthreads();
    for (int d = 1; d < 1024; d <<= 1) {
        int add = (t >= d) ? s[t - d] : 0;
        __syncthreads();
        s[t] += add;
        __syncthreads();
    }
    if (t < NB_SCAN) bsums[t] = s[t] - v;
}

__global__ void scan3_kernel(int* __restrict__ offs, const int* __restrict__ bsums,
                             int* __restrict__ cursor) {
    int i = blockIdx.x * 256 + threadIdx.x;
    if (i < NN) {
        int v = offs[i] + bsums[blockIdx.x];
        offs[i]   = v;
        cursor[i] = v;
    } else if (i == NN) {
        offs[i] = EE;
    }
}

// csre[p] = {src, dis[src]*dis[dst]} -- per-edge norm precomputed
__global__ void fill_kernel(const int* __restrict__ src, const int* __restrict__ dst,
                            const float* __restrict__ dis,
                            int* __restrict__ cursor, int2* __restrict__ csre) {
    int e = blockIdx.x * 256 + threadIdx.x;
    if (e < EE) {
        int s = src[e], d = dst[e];
        int p = atomicAdd(&cursor[d], 1);
        csre[p] = make_int2(s, __float_as_int(dis[s] * dis[d]));
    }
}

// ---------------------------------------------------------------------------
// Weight conversion f32 -> bf16 (strided rows)
// ---------------------------------------------------------------------------
__global__ void cvt_kernel(const float* __restrict__ src, __hip_bfloat16* __restrict__ dst,
                           int rows, int rlen, int sstride) {
    int idx = blockIdx.x * 256 + threadIdx.x;
    if (idx >= rows * rlen) return;
    int r = idx / rlen, c = idx - r * rlen;
    dst[idx] = __float2bfloat16(src[(size_t)r * sstride + c]);
}

// ---------------------------------------------------------------------------
// MFMA GEMM, W-resident-in-LDS variant. C[M,128] = epilogue(A[M,K] @ W[128,K]^T)
// 256 threads = 4 waves; each wave owns 32 rows x all 128 cols
// (2 row-blocks x 8 col-blocks of 16x16x32 MFMA). W staged to LDS once,
// A loaded global->VGPR directly in fragment layout. No barriers in K-loop.
// Epilogues: BIAS, ADDBF (bf16 Cadd), SILU, LNRES (SiLU+LN+f32 residual+bf16
// mirror), OUTDOT (row dot w2 -> outp), WF32/WBF plain stores.
// ---------------------------------------------------------------------------
template<int K, bool AF32, bool GATHER, bool BIAS, bool ADDBF, bool SILU,
         bool LNRES, bool OUTDOT, bool WF32, bool WBF>
__global__ __launch_bounds__(256, 2)
void mgemm2(const void* __restrict__ Avp, const __hip_bfloat16* __restrict__ W,
            const float* __restrict__ bias, const __hip_bfloat16* __restrict__ Cadd,
            const int* __restrict__ gidx, const float* __restrict__ lng,
            const float* __restrict__ lnb, float* __restrict__ hf,
            const float* __restrict__ w2, const float* __restrict__ b2,
            float* __restrict__ Cf, __hip_bfloat16* __restrict__ Cb,
            float* __restrict__ outp, int M)
{
    constexpr int PITCH = K + 4;         // shorts; +4 breaks 16-lane bank aliasing
    __shared__ short Ws[128 * PITCH];

    const int tid  = threadIdx.x;
    const int wave = tid >> 6;
    const int lane = tid & 63;
    const int l15  = lane & 15;
    const int quad = lane >> 4;          // 0..3
    const int m0   = blockIdx.x * 128;

    // ---- stage W once: [col][k] ----
    constexpr int CH = K / 8;            // short8 chunks per row
    #pragma unroll
    for (int it = 0; it < (128 * CH) / 256; ++it) {
        int idx = it * 256 + tid;
        int c   = idx / CH;
        int k8  = (idx - c * CH) * 8;
        short8 v = *(const short8*)(W + (size_t)c * K + k8);
        *(short8*)&Ws[c * PITCH + k8] = v;
    }
    __syncthreads();

    // ---- load A fragments (full K for this wave's 32 rows) ----
    const __hip_bfloat16* Ab = (const __hip_bfloat16*)Avp;
    const float*          Af = (const float*)Avp;
    int ridx0 = m0 + wave * 32 + l15;
    int ridx1 = ridx0 + 16;
    if (ridx0 >= M) ridx0 = M - 1;
    if (ridx1 >= M) ridx1 = M - 1;
    const int row0 = GATHER ? gidx[ridx0] : ridx0;
    const int row1 = GATHER ? gidx[ridx1] : ridx1;

    short8 afr[2][K / 32];
    #pragma unroll
    for (int kc = 0; kc < K / 32; ++kc) {
        int ko = kc * 32 + quad * 8;
        if (AF32) {
            const float* p0 = Af + (size_t)row0 * K + ko;
            const float* p1 = Af + (size_t)row1 * K + ko;
            float4 a0 = *(const float4*)p0, a1 = *(const float4*)(p0 + 4);
            float4 b0 = *(const float4*)p1, b1 = *(const float4*)(p1 + 4);
            float av[8] = {a0.x, a0.y, a0.z, a0.w, a1.x, a1.y, a1.z, a1.w};
            float bv[8] = {b0.x, b0.y, b0.z, b0.w, b1.x, b1.y, b1.z, b1.w};
            #pragma unroll
            for (int j = 0; j < 8; ++j) {
                afr[0][kc][j] = bf16bits(av[j]);
                afr[1][kc][j] = bf16bits(bv[j]);
            }
        } else {
            afr[0][kc] = *(const short8*)(Ab + (size_t)row0 * K + ko);
            afr[1][kc] = *(const short8*)(Ab + (size_t)row1 * K + ko);
        }
    }

    // ---- MFMA: 2 row-blocks x 8 col-blocks, K/32 chunks, no barriers ----
    floatx4 acc[2][8];
    #pragma unroll
    for (int mi = 0; mi < 2; ++mi)
        #pragma unroll
        for (int ni = 0; ni < 8; ++ni) acc[mi][ni] = (floatx4)0.f;

    #pragma unroll
    for (int kc = 0; kc < K / 32; ++kc) {
        int ko = kc * 32 + quad * 8;
        #pragma unroll
        for (int ni = 0; ni < 8; ++ni) {
            short8 b = *(const short8*)&Ws[(ni * 16 + l15) * PITCH + ko];
            acc[0][ni] = __builtin_amdgcn_mfma_f32_16x16x32_bf16(afr[0][kc], b, acc[0][ni], 0, 0, 0);
            acc[1][ni] = __builtin_amdgcn_mfma_f32_16x16x32_bf16(afr[1][kc], b, acc[1][ni], 0, 0, 0);
        }
    }

    // ---- epilogue preloads (col = ni*16 + l15) ----
    float bv[8], gv[8], lbv[8], w2v[8];
    #pragma unroll
    for (int ni = 0; ni < 8; ++ni) {
        int col = ni * 16 + l15;
        if (BIAS)   bv[ni]  = bias[col];
        if (LNRES) { gv[ni] = lng[col]; lbv[ni] = lnb[col]; }
        if (OUTDOT) w2v[ni] = w2[col];
    }
    const float b2v = OUTDOT ? b2[0] : 0.f;

    // D layout per col-block: row = quad*4 + r, col = ni*16 + l15
    #pragma unroll
    for (int mi = 0; mi < 2; ++mi) {
        #pragma unroll
        for (int r = 0; r < 4; ++r) {
            const int m = m0 + wave * 32 + mi * 16 + quad * 4 + r;
            if (LNRES) {
                float sv[8], p1 = 0.f, p2 = 0.f;
                #pragma unroll
                for (int ni = 0; ni < 8; ++ni) {
                    float v = acc[mi][ni][r] + bv[ni];
                    v = v / (1.f + __expf(-v));          // silu
                    sv[ni] = v; p1 += v; p2 += v * v;
                }
                #pragma unroll
                for (int o = 1; o < 16; o <<= 1) {       // 16-lane butterfly (in quad)
                    p1 += __shfl_xor(p1, o);
                    p2 += __shfl_xor(p2, o);
                }
                float mu  = p1 * (1.f / 128.f);
                float var = p2 * (1.f / 128.f) - mu * mu;
                float rs  = rsqrtf(var + LN_EPS);
                if (m < M) {
                    #pragma unroll
                    for (int ni = 0; ni < 8; ++ni) {
                        int col = ni * 16 + l15;
                        float y  = (sv[ni] - mu) * rs * gv[ni] + lbv[ni];
                        float hn = hf[(size_t)m * HD + col] + y;
                        hf[(size_t)m * HD + col] = hn;
                        Cb[(size_t)m * HD + col] = __float2bfloat16(hn);
                    }
                }
            } else if (OUTDOT) {
                float p = 0.f;
                #pragma unroll
                for (int ni = 0; ni < 8; ++ni) {
                    float v = acc[mi][ni][r];
                    if (BIAS)  v += bv[ni];
                    if (ADDBF && m < M)
                        v += __bfloat162float(Cadd[(size_t)m * HD + ni * 16 + l15]);
                    if (SILU)  v = v / (1.f + __expf(-v));
                    p += v * w2v[ni];
                }
                #pragma unroll
                for (int o = 1; o < 16; o <<= 1) p += __shfl_xor(p, o);
                if (l15 == 0 && m < M) outp[m] = p + b2v;
            } else {
                if (m < M) {
                    #pragma unroll
                    for (int ni = 0; ni < 8; ++ni) {
                        int col = ni * 16 + l15;
                        float v = acc[mi][ni][r];
                        if (BIAS)  v += bv[ni];
                        if (ADDBF) v += __bfloat162float(Cadd[(size_t)m * HD + col]);
                        if (SILU)  v = v / (1.f + __expf(-v));
                        if (WF32)  Cf[(size_t)m * HD + col] = v;
                        if (WBF)   Cb[(size_t)m * HD + col] = __float2bfloat16(v);
                    }
                }
            }
        }
    }
}

// ---------------------------------------------------------------------------
// Pure aggregation (linearity swap: aggregate h BEFORE the conv GEMM).
// agg[n] = self_n*h[n] + sum_e norm_e * h[src_e]. One wave/node, bf16x2/lane.
// ---------------------------------------------------------------------------
__global__ __launch_bounds__(256)
void agg_kernel(const unsigned int* __restrict__ hbfu, const float* __restrict__ dis,
                const int* __restrict__ offs, const int2* __restrict__ csre,
                unsigned int* __restrict__ aggu)
{
    const int lane = threadIdx.x & 63;
    const int n    = blockIdx.x * 4 + (threadIdx.x >> 6);   // NN % 4 == 0

    const float dn = dis[n];
    float2 sf = unpack_bf2(hbfu[(size_t)n * 64 + lane]);
    float acc0 = sf.x * (dn * dn);
    float acc1 = sf.y * (dn * dn);

    int e  = offs[n];
    int e1 = offs[n + 1];
    for (; e + 2 <= e1; e += 2) {
        int2 ea = csre[e];
        int2 eb = csre[e + 1];
        unsigned int pa = hbfu[(size_t)ea.x * 64 + lane];
        unsigned int pb = hbfu[(size_t)eb.x * 64 + lane];
        float wa = __int_as_float(ea.y);
        float wb = __int_as_float(eb.y);
        float2 fa = unpack_bf2(pa);
        float2 fb = unpack_bf2(pb);
        acc0 += wa * fa.x + wb * fb.x;
        acc1 += wa * fa.y + wb * fb.y;
    }
    if (e < e1) {
        int2 ea = csre[e];
        unsigned int pa = hbfu[(size_t)ea.x * 64 + lane];
        float wa = __int_as_float(ea.y);
        float2 fa = unpack_bf2(pa);
        acc0 += wa * fa.x;
        acc1 += wa * fa.y;
    }
    aggu[(size_t)n * 64 + lane] = pack_bf2(acc0, acc1);
}

// ---------------------------------------------------------------------------
// Graph pooling: offsets via binary search (batch_vec sorted), then mean -> bf16.
// ---------------------------------------------------------------------------
__global__ void goff_kernel(const int* __restrict__ bv, int* __restrict__ goff) {
    int g = blockIdx.x * 256 + threadIdx.x;
    if (g > GG) return;
    int lo = 0, hi = NN;
    while (lo < hi) {
        int mid = (lo + hi) >> 1;
        if (bv[mid] < g) lo = mid + 1; else hi = mid;
    }
    goff[g] = lo;
}

__global__ __launch_bounds__(128)
void pool_kernel(const float* __restrict__ h, const int* __restrict__ goff,
                 __hip_bfloat16* __restrict__ emb)
{
    int g = blockIdx.x;
    int f = threadIdx.x;
    int i0 = goff[g], i1 = goff[g + 1];
    float s = 0.f;
    for (int i = i0; i < i1; ++i) s += h[(size_t)i * HD + f];
    float c = (float)(i1 - i0);
    emb[(size_t)g * HD + f] = __float2bfloat16(s / fmaxf(c, 1.f));
}

// ---------------------------------------------------------------------------
// Launcher
// ---------------------------------------------------------------------------
extern "C" void kernel_launch(void* const* d_in, const int* in_sizes, int n_in,
                              void* d_out, int out_size, void* d_ws, size_t ws_size,
                              hipStream_t stream)
{
    const float* x        = (const float*)d_in[0];
    const int*   eidx     = (const int*)d_in[1];
    const int*   batchv   = (const int*)d_in[2];
    const float* in_w     = (const float*)d_in[3];
    const float* in_b     = (const float*)d_in[4];
    const float* conv_w   = (const float*)d_in[5];
    const float* conv_b   = (const float*)d_in[6];
    const float* ln_g     = (const float*)d_in[7];
    const float* ln_b     = (const float*)d_in[8];
    const float* phys_w1  = (const float*)d_in[9];
    const float* phys_b1  = (const float*)d_in[10];
    const float* phys_w2  = (const float*)d_in[11];
    const float* phys_b2  = (const float*)d_in[12];
    const float* head_w1  = (const float*)d_in[13];
    const float* head_b1  = (const float*)d_in[14];
    const float* head_w2  = (const float*)d_in[15];
    const float* head_b2  = (const float*)d_in[16];
    float* out = (float*)d_out;

    const int* esrc = eidx;
    const int* edst = eidx + EE;

    // workspace layout
    char* base = (char*)d_ws;
    size_t off = 0;
    auto alloc = [&](size_t bytes) {
        char* p = base + off;
        off = (off + bytes + 255) & ~(size_t)255;
        return p;
    };
    float*          h      = (float*)alloc((size_t)NN * HD * 4);
    __hip_bfloat16* hbf    = (__hip_bfloat16*)alloc((size_t)NN * HD * 2);
    __hip_bfloat16* bufA   = (__hip_bfloat16*)alloc((size_t)NN * HD * 2);
    float*          dis    = (float*)alloc((size_t)NN * 4);
    int*            degi   = (int*)  alloc((size_t)NN * 4);
    int*            offs   = (int*)  alloc((size_t)(NN + 1) * 4);
    int*            cursor = (int*)  alloc((size_t)NN * 4);
    int2*           csre   = (int2*) alloc((size_t)EE * 8);
    __hip_bfloat16* emb    = (__hip_bfloat16*)alloc((size_t)GG * HD * 2);
    int*            goff   = (int*)  alloc((size_t)(GG + 1) * 4);
    int*            bsums  = (int*)  alloc(1024 * 4);
    __hip_bfloat16* w_in   = (__hip_bfloat16*)alloc(HD * DIN * 2);
    __hip_bfloat16* w_conv = (__hip_bfloat16*)alloc((size_t)NL * HD * HD * 2);
    __hip_bfloat16* w_p1   = (__hip_bfloat16*)alloc(HD * HD * 2);
    __hip_bfloat16* w_p2   = (__hip_bfloat16*)alloc(HD * HD * 2);
    __hip_bfloat16* w_h1a  = (__hip_bfloat16*)alloc(HD * HD * 2);
    __hip_bfloat16* w_h1b  = (__hip_bfloat16*)alloc(HD * HD * 2);
    (void)ws_size; (void)n_in; (void)in_sizes; (void)out_size;

    const int GB = (NN + 127) / 128;   // 1563 GEMM blocks

    // --- weight conversion (tiny) ---
    cvt_kernel<<<(HD * DIN + 255) / 256, 256, 0, stream>>>(in_w, w_in, HD, DIN, DIN);
    cvt_kernel<<<(NL * HD * HD + 255) / 256, 256, 0, stream>>>(conv_w, w_conv, NL * HD, HD, HD);
    cvt_kernel<<<(HD * HD + 255) / 256, 256, 0, stream>>>(phys_w1, w_p1, HD, HD, HD);
    cvt_kernel<<<(HD * HD + 255) / 256, 256, 0, stream>>>(phys_w2, w_p2, HD, HD, HD);
    cvt_kernel<<<(HD * HD + 255) / 256, 256, 0, stream>>>(head_w1, w_h1a, HD, HD, 2 * HD);
    cvt_kernel<<<(HD * HD + 255) / 256, 256, 0, stream>>>(head_w1 + HD, w_h1b, HD, HD, 2 * HD);

    // --- CSR build ---
    hipMemsetAsync(degi, 0, (size_t)NN * 4, stream);
    hist_kernel<<<(EE + 255) / 256, 256, 0, stream>>>(edst, degi);
    dis_kernel<<<(NN + 255) / 256, 256, 0, stream>>>(degi, dis);
    scan1_kernel<<<NB_SCAN, 256, 0, stream>>>(degi, offs, bsums);
    scan2_kernel<<<1, 1024, 0, stream>>>(bsums);
    scan3_kernel<<<NB_SCAN, 256, 0, stream>>>(offs, bsums, cursor);
    fill_kernel<<<(EE + 255) / 256, 256, 0, stream>>>(esrc, edst, dis, cursor, csre);

    // --- input projection: h = x @ in_w.T + in_b (f32 -> bf16 on the fly) ---
    mgemm2<DIN, true, false, true, false, false, false, false, true, true>
        <<<GB, 256, 0, stream>>>(x, w_in, in_b, nullptr, nullptr, nullptr, nullptr,
                                 nullptr, nullptr, nullptr, h, hbf, nullptr, NN);

    // --- GCN layers: agg first (linearity), then GEMM with fused SiLU+LN+residual ---
    for (int l = 0; l < NL; ++l) {
        agg_kernel<<<NN / 4, 256, 0, stream>>>(
            (const unsigned int*)hbf, dis, offs, csre, (unsigned int*)bufA);
        mgemm2<HD, false, false, true, false, false, true, false, false, false>
            <<<GB, 256, 0, stream>>>(bufA, w_conv + (size_t)l * HD * HD,
                                     conv_b + l * HD, nullptr, nullptr,
                                     ln_g + l * HD, ln_b + l * HD, h,
                                     nullptr, nullptr, nullptr, hbf, nullptr, NN);
    }

    // --- graph mean pooling (bf16 emb) ---
    goff_kernel<<<(GG + 256) / 256, 256, 0, stream>>>(batchv, goff);
    pool_kernel<<<GG, 128, 0, stream>>>(h, goff, emb);

    // --- phys MLP: t1 = silu(h@w1+b1) -> bufA ; hbf = t1@w2 + b2 + hbf ---
    mgemm2<HD, false, false, true, false, true, false, false, false, true>
        <<<GB, 256, 0, stream>>>(hbf, w_p1, phys_b1, nullptr, nullptr, nullptr, nullptr,
                                 nullptr, nullptr, nullptr, nullptr, bufA, nullptr, NN);
    mgemm2<HD, false, false, true, true, false, false, false, false, true>
        <<<GB, 256, 0, stream>>>(bufA, w_p2, phys_b2, hbf, nullptr, nullptr, nullptr,
                                 nullptr, nullptr, nullptr, nullptr, hbf, nullptr, NN);

    // --- head: t2 = P@W1a^T -> bufA ---
    mgemm2<HD, false, false, false, false, false, false, false, false, true>
        <<<GB, 256, 0, stream>>>(hbf, w_h1a, nullptr, nullptr, nullptr, nullptr, nullptr,
                                 nullptr, nullptr, nullptr, nullptr, bufA, nullptr, NN);
    // --- head2 fused: out = silu(emb[batch]@W1b^T + t2 + b1) . w2 + b2 ---
    mgemm2<HD, false, true, true, true, true, false, true, false, false>
        <<<GB, 256, 0, stream>>>(emb, w_h1b, head_b1, bufA, batchv, nullptr, nullptr,
                                 nullptr, head_w2, head_b2, nullptr, nullptr, out, NN);
}

// Round 6
// 779.742 us; speedup vs baseline: 1.0548x; 1.0548x over previous
//
#include <hip/hip_runtime.h>
#include <hip/hip_bf16.h>
#include <math.h>

// Problem constants (fixed-size problem)
#define NN      200000   // nodes
#define EE      600000   // directed edges
#define GG      8192     // graphs
#define DIN     64       // input dim
#define HD      128      // hidden dim
#define NL      4        // layers
#define LN_EPS  1e-5f

static constexpr int NB_SCAN = (NN + 255) / 256;   // 782 blocks for node scan

typedef __attribute__((ext_vector_type(8))) short short8;   // 8 bf16 (4 VGPRs)
typedef __attribute__((ext_vector_type(4))) float floatx4;  // MFMA accumulator

// bf16x2 <-> float2 (exact: bf16->f32 is a 16-bit shift)
__device__ inline float2 unpack_bf2(unsigned int p) {
    return make_float2(__uint_as_float(p << 16), __uint_as_float(p & 0xffff0000u));
}
__device__ inline unsigned int pack_bf2(float a, float b) {
    __hip_bfloat16 lo = __float2bfloat16(a);
    __hip_bfloat16 hi = __float2bfloat16(b);
    unsigned short ul = *reinterpret_cast<unsigned short*>(&lo);
    unsigned short uh = *reinterpret_cast<unsigned short*>(&hi);
    return (unsigned int)ul | ((unsigned int)uh << 16);
}
__device__ inline short bf16bits(float x) {
    __hip_bfloat16 t = __float2bfloat16(x);
    return *reinterpret_cast<short*>(&t);
}

// ---------------------------------------------------------------------------
// CSR build: degree histogram -> exclusive scan -> edge fill (with edge norm)
// ---------------------------------------------------------------------------
__global__ void hist_kernel(const int* __restrict__ dst, int* __restrict__ degi) {
    int e = blockIdx.x * 256 + threadIdx.x;
    if (e < EE) atomicAdd(&degi[dst[e]], 1);
}

__global__ void dis_kernel(const int* __restrict__ degi, float* __restrict__ dis) {
    int n = blockIdx.x * 256 + threadIdx.x;
    if (n < NN) dis[n] = rsqrtf((float)degi[n] + 1.0f);
}

__global__ void scan1_kernel(const int* __restrict__ degi, int* __restrict__ offs,
                             int* __restrict__ bsums) {
    __shared__ int s[256];
    int t = threadIdx.x;
    int i = blockIdx.x * 256 + t;
    int v = (i < NN) ? degi[i] : 0;
    s[t] = v;
    __syncthreads();
    for (int d = 1; d < 256; d <<= 1) {
        int add = (t >= d) ? s[t - d] : 0;
        __syncthreads();
        s[t] += add;
        __syncthreads();
    }
    if (i < NN) offs[i] = s[t] - v;
    if (t == 255) bsums[blockIdx.x] = s[255];
}

__global__ void scan2_kernel(int* __restrict__ bsums) {
    __shared__ int s[1024];
    int t = threadIdx.x;
    int v = (t < NB_SCAN) ? bsums[t] : 0;
    s[t] = v;
    __syncthreads();
    for (int d = 1; d < 1024; d <<= 1) {
        int add = (t >= d) ? s[t - d] : 0;
        __syncthreads();
        s[t] += add;
        __syncthreads();
    }
    if (t < NB_SCAN) bsums[t] = s[t] - v;
}

__global__ void scan3_kernel(int* __restrict__ offs, const int* __restrict__ bsums,
                             int* __restrict__ cursor) {
    int i = blockIdx.x * 256 + threadIdx.x;
    if (i < NN) {
        int v = offs[i] + bsums[blockIdx.x];
        offs[i]   = v;
        cursor[i] = v;
    } else if (i == NN) {
        offs[i] = EE;
    }
}

// csre[p] = {src, dis[src]*dis[dst]} -- per-edge norm precomputed
__global__ void fill_kernel(const int* __restrict__ src, const int* __restrict__ dst,
                            const float* __restrict__ dis,
                            int* __restrict__ cursor, int2* __restrict__ csre) {
    int e = blockIdx.x * 256 + threadIdx.x;
    if (e < EE) {
        int s = src[e], d = dst[e];
        int p = atomicAdd(&cursor[d], 1);
        csre[p] = make_int2(s, __float_as_int(dis[s] * dis[d]));
    }
}

// ---------------------------------------------------------------------------
// Weight conversion f32 -> bf16 (strided rows)
// ---------------------------------------------------------------------------
__global__ void cvt_kernel(const float* __restrict__ src, __hip_bfloat16* __restrict__ dst,
                           int rows, int rlen, int sstride) {
    int idx = blockIdx.x * 256 + threadIdx.x;
    if (idx >= rows * rlen) return;
    int r = idx / rlen, c = idx - r * rlen;
    dst[idx] = __float2bfloat16(src[(size_t)r * sstride + c]);
}

// ---------------------------------------------------------------------------
// Precompute fused tail weight: wf[i][0:128] = W1a[i][:],
// wf[i][128:256] = (W1a @ phys_w2)[i][:], biasf[i] = dot(W1a[i], phys_b2).
// head_w1 is [128][256]; W1a = cols 0..127. Block i (128 blocks), thread j.
// ---------------------------------------------------------------------------
__global__ __launch_bounds__(128)
void pm_kernel(const float* __restrict__ head_w1, const float* __restrict__ phys_w2,
               const float* __restrict__ phys_b2, __hip_bfloat16* __restrict__ wf,
               float* __restrict__ biasf)
{
    int i = blockIdx.x;
    int j = threadIdx.x;
    const float* w1a = head_w1 + (size_t)i * 256;
    wf[(size_t)i * 256 + j] = __float2bfloat16(w1a[j]);
    float m = 0.f;
    #pragma unroll 4
    for (int c = 0; c < 128; ++c) m += w1a[c] * phys_w2[(size_t)c * 128 + j];
    wf[(size_t)i * 256 + 128 + j] = __float2bfloat16(m);

    float t = w1a[j] * phys_b2[j];
    #pragma unroll
    for (int o = 32; o > 0; o >>= 1) t += __shfl_down(t, o);
    __shared__ float red[2];
    if ((j & 63) == 0) red[j >> 6] = t;
    __syncthreads();
    if (j == 0) biasf[i] = red[0] + red[1];
}

// ---------------------------------------------------------------------------
// MFMA GEMM, zero-LDS: B-fragments load straight from global (W is L2-hot).
// C[M,128] = epilogue(A[M,K] @ W[128,K]^T). 256 threads = 4 waves; each wave
// owns 32 rows x 128 cols (2 row-blocks x 8 col-blocks of 16x16x32 MFMA).
// CONCAT: K=256 with A = [A1 | A2] (two 128-wide bf16 buffers).
// LNRES: v=silu(acc+bias); LN over 128 cols (16-lane butterfly); bf16
// residual read-modify-write on Cb.
// ---------------------------------------------------------------------------
template<int K, bool AF32, bool CONCAT, bool BIAS, bool SILU, bool LNRES,
         bool WF32, bool WBF>
__global__ __launch_bounds__(256, 2)
void mgemm3(const void* __restrict__ A1vp, const void* __restrict__ A2vp,
            const __hip_bfloat16* __restrict__ W,
            const float* __restrict__ bias,
            const float* __restrict__ lng, const float* __restrict__ lnb,
            float* __restrict__ Cf, __hip_bfloat16* __restrict__ Cb, int M)
{
    const int tid  = threadIdx.x;
    const int wave = tid >> 6;
    const int lane = tid & 63;
    const int l15  = lane & 15;
    const int quad = lane >> 4;
    const int m0   = blockIdx.x * 128;

    int ridx0 = m0 + wave * 32 + l15;
    int ridx1 = ridx0 + 16;
    if (ridx0 >= M) ridx0 = M - 1;
    if (ridx1 >= M) ridx1 = M - 1;

    constexpr int NC = K / 32;
    short8 afr[2][NC];
    const __hip_bfloat16* A1 = (const __hip_bfloat16*)A1vp;
    const __hip_bfloat16* A2 = (const __hip_bfloat16*)A2vp;
    const float*          A1f = (const float*)A1vp;

    #pragma unroll
    for (int kc = 0; kc < NC; ++kc) {
        if (CONCAT) {
            const __hip_bfloat16* src = (kc < NC / 2) ? A1 : A2;
            int ko = (kc & (NC / 2 - 1)) * 32 + quad * 8;
            afr[0][kc] = *(const short8*)(src + (size_t)ridx0 * (K / 2) + ko);
            afr[1][kc] = *(const short8*)(src + (size_t)ridx1 * (K / 2) + ko);
        } else if (AF32) {
            int ko = kc * 32 + quad * 8;
            const float* p0 = A1f + (size_t)ridx0 * K + ko;
            const float* p1 = A1f + (size_t)ridx1 * K + ko;
            float4 a0 = *(const float4*)p0, a1 = *(const float4*)(p0 + 4);
            float4 b0 = *(const float4*)p1, b1 = *(const float4*)(p1 + 4);
            float av[8] = {a0.x, a0.y, a0.z, a0.w, a1.x, a1.y, a1.z, a1.w};
            float bw[8] = {b0.x, b0.y, b0.z, b0.w, b1.x, b1.y, b1.z, b1.w};
            #pragma unroll
            for (int j = 0; j < 8; ++j) {
                afr[0][kc][j] = bf16bits(av[j]);
                afr[1][kc][j] = bf16bits(bw[j]);
            }
        } else {
            int ko = kc * 32 + quad * 8;
            afr[0][kc] = *(const short8*)(A1 + (size_t)ridx0 * K + ko);
            afr[1][kc] = *(const short8*)(A1 + (size_t)ridx1 * K + ko);
        }
    }

    floatx4 acc[2][8];
    #pragma unroll
    for (int mi = 0; mi < 2; ++mi)
        #pragma unroll
        for (int ni = 0; ni < 8; ++ni) acc[mi][ni] = (floatx4)0.f;

    const short* Ws = (const short*)W;
    #pragma unroll
    for (int kc = 0; kc < NC; ++kc) {
        int ko = kc * 32 + quad * 8;
        #pragma unroll
        for (int ni = 0; ni < 8; ++ni) {
            short8 b = *(const short8*)(Ws + (size_t)(ni * 16 + l15) * K + ko);
            acc[0][ni] = __builtin_amdgcn_mfma_f32_16x16x32_bf16(afr[0][kc], b, acc[0][ni], 0, 0, 0);
            acc[1][ni] = __builtin_amdgcn_mfma_f32_16x16x32_bf16(afr[1][kc], b, acc[1][ni], 0, 0, 0);
        }
    }

    // epilogue preloads (col = ni*16 + l15)
    float bv[8], gv[8], lbv[8];
    #pragma unroll
    for (int ni = 0; ni < 8; ++ni) {
        int col = ni * 16 + l15;
        if (BIAS)   bv[ni]  = bias[col];
        if (LNRES) { gv[ni] = lng[col]; lbv[ni] = lnb[col]; }
    }

    #pragma unroll
    for (int mi = 0; mi < 2; ++mi) {
        #pragma unroll
        for (int r = 0; r < 4; ++r) {
            const int m = m0 + wave * 32 + mi * 16 + quad * 4 + r;
            if (LNRES) {
                float sv[8], p1 = 0.f, p2 = 0.f;
                #pragma unroll
                for (int ni = 0; ni < 8; ++ni) {
                    float v = acc[mi][ni][r] + bv[ni];
                    v = v / (1.f + __expf(-v));          // silu
                    sv[ni] = v; p1 += v; p2 += v * v;
                }
                #pragma unroll
                for (int o = 1; o < 16; o <<= 1) {       // 16-lane butterfly
                    p1 += __shfl_xor(p1, o);
                    p2 += __shfl_xor(p2, o);
                }
                float mu  = p1 * (1.f / 128.f);
                float var = p2 * (1.f / 128.f) - mu * mu;
                float rs  = rsqrtf(var + LN_EPS);
                if (m < M) {
                    #pragma unroll
                    for (int ni = 0; ni < 8; ++ni) {
                        int col = ni * 16 + l15;
                        float y  = (sv[ni] - mu) * rs * gv[ni] + lbv[ni];
                        float hn = __bfloat162float(Cb[(size_t)m * HD + col]) + y;
                        Cb[(size_t)m * HD + col] = __float2bfloat16(hn);
                    }
                }
            } else if (m < M) {
                #pragma unroll
                for (int ni = 0; ni < 8; ++ni) {
                    int col = ni * 16 + l15;
                    float v = acc[mi][ni][r];
                    if (BIAS) v += bv[ni];
                    if (SILU) v = v / (1.f + __expf(-v));
                    if (WF32) Cf[(size_t)m * HD + col] = v;
                    if (WBF)  Cb[(size_t)m * HD + col] = __float2bfloat16(v);
                }
            }
        }
    }
}

// ---------------------------------------------------------------------------
// Aggregation: 16 lanes per node (uint4 = 8 bf16 features/lane), 4 nodes per
// wave -> 4 independent edge streams per wave. x2 unroll inside each stream.
// agg[n] = self_n*h[n] + sum_e norm_e * h[src_e].
// ---------------------------------------------------------------------------
__global__ __launch_bounds__(256)
void agg_kernel(const uint4* __restrict__ hb4, const float* __restrict__ dis,
                const int* __restrict__ offs, const int2* __restrict__ csre,
                uint4* __restrict__ agg4)
{
    const int lane = threadIdx.x & 63;
    const int l16  = lane & 15;
    const int w    = (blockIdx.x * 256 + threadIdx.x) >> 6;
    const int n    = w * 4 + (lane >> 4);       // NN % 16 == 0 at grid level

    const float dn = dis[n];
    uint4 sp = hb4[(size_t)n * 16 + l16];
    float acc[8];
    {
        float s = dn * dn;
        float2 f0 = unpack_bf2(sp.x), f1 = unpack_bf2(sp.y);
        float2 f2 = unpack_bf2(sp.z), f3 = unpack_bf2(sp.w);
        acc[0] = f0.x * s; acc[1] = f0.y * s;
        acc[2] = f1.x * s; acc[3] = f1.y * s;
        acc[4] = f2.x * s; acc[5] = f2.y * s;
        acc[6] = f3.x * s; acc[7] = f3.y * s;
    }

    int e  = offs[n];
    int e1 = offs[n + 1];
    for (; e + 2 <= e1; e += 2) {
        int2 ea = csre[e];
        int2 eb = csre[e + 1];
        uint4 pa = hb4[(size_t)ea.x * 16 + l16];
        uint4 pb = hb4[(size_t)eb.x * 16 + l16];
        float wa = __int_as_float(ea.y);
        float wb = __int_as_float(eb.y);
        float2 a0 = unpack_bf2(pa.x), a1 = unpack_bf2(pa.y);
        float2 a2 = unpack_bf2(pa.z), a3 = unpack_bf2(pa.w);
        float2 b0 = unpack_bf2(pb.x), b1 = unpack_bf2(pb.y);
        float2 b2 = unpack_bf2(pb.z), b3 = unpack_bf2(pb.w);
        acc[0] += wa * a0.x + wb * b0.x; acc[1] += wa * a0.y + wb * b0.y;
        acc[2] += wa * a1.x + wb * b1.x; acc[3] += wa * a1.y + wb * b1.y;
        acc[4] += wa * a2.x + wb * b2.x; acc[5] += wa * a2.y + wb * b2.y;
        acc[6] += wa * a3.x + wb * b3.x; acc[7] += wa * a3.y + wb * b3.y;
    }
    if (e < e1) {
        int2 ea = csre[e];
        uint4 pa = hb4[(size_t)ea.x * 16 + l16];
        float wa = __int_as_float(ea.y);
        float2 a0 = unpack_bf2(pa.x), a1 = unpack_bf2(pa.y);
        float2 a2 = unpack_bf2(pa.z), a3 = unpack_bf2(pa.w);
        acc[0] += wa * a0.x; acc[1] += wa * a0.y;
        acc[2] += wa * a1.x; acc[3] += wa * a1.y;
        acc[4] += wa * a2.x; acc[5] += wa * a2.y;
        acc[6] += wa * a3.x; acc[7] += wa * a3.y;
    }

    uint4 o;
    o.x = pack_bf2(acc[0], acc[1]);
    o.y = pack_bf2(acc[2], acc[3]);
    o.z = pack_bf2(acc[4], acc[5]);
    o.w = pack_bf2(acc[6], acc[7]);
    agg4[(size_t)n * 16 + l16] = o;
}

// ---------------------------------------------------------------------------
// Graph pooling: offsets via binary search (batch_vec sorted), mean -> bf16.
// 64 threads per graph, uint (bf16x2) per thread.
// ---------------------------------------------------------------------------
__global__ void goff_kernel(const int* __restrict__ bv, int* __restrict__ goff) {
    int g = blockIdx.x * 256 + threadIdx.x;
    if (g > GG) return;
    int lo = 0, hi = NN;
    while (lo < hi) {
        int mid = (lo + hi) >> 1;
        if (bv[mid] < g) lo = mid + 1; else hi = mid;
    }
    goff[g] = lo;
}

__global__ __launch_bounds__(64)
void pool_kernel(const unsigned int* __restrict__ hu, const int* __restrict__ goff,
                 unsigned int* __restrict__ embu)
{
    int g = blockIdx.x;
    int f = threadIdx.x;          // 0..63
    int i0 = goff[g], i1 = goff[g + 1];
    float s0 = 0.f, s1 = 0.f;
    for (int i = i0; i < i1; ++i) {
        float2 v = unpack_bf2(hu[(size_t)i * 64 + f]);
        s0 += v.x; s1 += v.y;
    }
    float c = fmaxf((float)(i1 - i0), 1.f);
    embu[(size_t)g * 64 + f] = pack_bf2(s0 / c, s1 / c);
}

// ---------------------------------------------------------------------------
// Final head: out[n] = dot(silu(t2[n] + embp[batch[n]]), w2) + b2.
// One wave per node, 2 features per lane.
// ---------------------------------------------------------------------------
__global__ __launch_bounds__(256)
void final_kernel(const unsigned int* __restrict__ t2u, const float2* __restrict__ embp2,
                  const int* __restrict__ bv, const float* __restrict__ w2,
                  const float* __restrict__ b2, float* __restrict__ out)
{
    int gw   = (blockIdx.x * 256 + threadIdx.x) >> 6;
    int lane = threadIdx.x & 63;
    if (gw >= NN) return;
    int g = bv[gw];
    float2 t = unpack_bf2(t2u[(size_t)gw * 64 + lane]);
    float2 e = embp2[(size_t)g * 64 + lane];
    float v0 = t.x + e.x, v1 = t.y + e.y;
    v0 = v0 / (1.f + __expf(-v0));
    v1 = v1 / (1.f + __expf(-v1));
    float2 wv = *((const float2*)w2 + lane);
    float s = v0 * wv.x + v1 * wv.y;
    #pragma unroll
    for (int o = 32; o > 0; o >>= 1) s += __shfl_down(s, o);
    if (lane == 0) out[gw] = s + b2[0];
}

// ---------------------------------------------------------------------------
// Launcher
// ---------------------------------------------------------------------------
extern "C" void kernel_launch(void* const* d_in, const int* in_sizes, int n_in,
                              void* d_out, int out_size, void* d_ws, size_t ws_size,
                              hipStream_t stream)
{
    const float* x        = (const float*)d_in[0];
    const int*   eidx     = (const int*)d_in[1];
    const int*   batchv   = (const int*)d_in[2];
    const float* in_w     = (const float*)d_in[3];
    const float* in_b     = (const float*)d_in[4];
    const float* conv_w   = (const float*)d_in[5];
    const float* conv_b   = (const float*)d_in[6];
    const float* ln_g     = (const float*)d_in[7];
    const float* ln_b     = (const float*)d_in[8];
    const float* phys_w1  = (const float*)d_in[9];
    const float* phys_b1  = (const float*)d_in[10];
    const float* phys_w2  = (const float*)d_in[11];
    const float* phys_b2  = (const float*)d_in[12];
    const float* head_w1  = (const float*)d_in[13];
    const float* head_b1  = (const float*)d_in[14];
    const float* head_w2  = (const float*)d_in[15];
    const float* head_b2  = (const float*)d_in[16];
    float* out = (float*)d_out;

    const int* esrc = eidx;
    const int* edst = eidx + EE;

    // workspace layout (~170 MB)
    char* base = (char*)d_ws;
    size_t off = 0;
    auto alloc = [&](size_t bytes) {
        char* p = base + off;
        off = (off + bytes + 255) & ~(size_t)255;
        return p;
    };
    __hip_bfloat16* hbf    = (__hip_bfloat16*)alloc((size_t)NN * HD * 2);
    __hip_bfloat16* bufA   = (__hip_bfloat16*)alloc((size_t)NN * HD * 2);
    __hip_bfloat16* bufB   = (__hip_bfloat16*)alloc((size_t)NN * HD * 2);
    float*          dis    = (float*)alloc((size_t)NN * 4);
    int*            degi   = (int*)  alloc((size_t)NN * 4);
    int*            offs   = (int*)  alloc((size_t)(NN + 1) * 4);
    int*            cursor = (int*)  alloc((size_t)NN * 4);
    int2*           csre   = (int2*) alloc((size_t)EE * 8);
    __hip_bfloat16* emb    = (__hip_bfloat16*)alloc((size_t)GG * HD * 2);
    float*          embp   = (float*)alloc((size_t)GG * HD * 4);
    int*            goff   = (int*)  alloc((size_t)(GG + 1) * 4);
    int*            bsums  = (int*)  alloc(1024 * 4);
    __hip_bfloat16* w_in   = (__hip_bfloat16*)alloc(HD * DIN * 2);
    __hip_bfloat16* w_conv = (__hip_bfloat16*)alloc((size_t)NL * HD * HD * 2);
    __hip_bfloat16* w_p1   = (__hip_bfloat16*)alloc(HD * HD * 2);
    __hip_bfloat16* w_h1b  = (__hip_bfloat16*)alloc(HD * HD * 2);
    __hip_bfloat16* wf     = (__hip_bfloat16*)alloc(HD * 2 * HD * 2);
    float*          biasf  = (float*)alloc(HD * 4);
    (void)ws_size; (void)n_in; (void)in_sizes; (void)out_size;

    const int GB = (NN + 127) / 128;   // 1563 GEMM blocks

    // --- weight prep (tiny) ---
    cvt_kernel<<<(HD * DIN + 255) / 256, 256, 0, stream>>>(in_w, w_in, HD, DIN, DIN);
    cvt_kernel<<<(NL * HD * HD + 255) / 256, 256, 0, stream>>>(conv_w, w_conv, NL * HD, HD, HD);
    cvt_kernel<<<(HD * HD + 255) / 256, 256, 0, stream>>>(phys_w1, w_p1, HD, HD, HD);
    cvt_kernel<<<(HD * HD + 255) / 256, 256, 0, stream>>>(head_w1 + HD, w_h1b, HD, HD, 2 * HD);
    pm_kernel<<<HD, HD, 0, stream>>>(head_w1, phys_w2, phys_b2, wf, biasf);

    // --- CSR build ---
    hipMemsetAsync(degi, 0, (size_t)NN * 4, stream);
    hist_kernel<<<(EE + 255) / 256, 256, 0, stream>>>(edst, degi);
    dis_kernel<<<(NN + 255) / 256, 256, 0, stream>>>(degi, dis);
    scan1_kernel<<<NB_SCAN, 256, 0, stream>>>(degi, offs, bsums);
    scan2_kernel<<<1, 1024, 0, stream>>>(bsums);
    scan3_kernel<<<NB_SCAN, 256, 0, stream>>>(offs, bsums, cursor);
    fill_kernel<<<(EE + 255) / 256, 256, 0, stream>>>(esrc, edst, dis, cursor, csre);

    // --- input projection: hbf = x @ in_w.T + in_b ---
    mgemm3<DIN, true, false, true, false, false, false, true>
        <<<GB, 256, 0, stream>>>(x, nullptr, w_in, in_b, nullptr, nullptr,
                                 nullptr, hbf, NN);

    // --- GCN layers: agg first (linearity), then GEMM w/ fused SiLU+LN+bf16 residual ---
    for (int l = 0; l < NL; ++l) {
        agg_kernel<<<NN / 16, 256, 0, stream>>>(
            (const uint4*)hbf, dis, offs, csre, (uint4*)bufA);
        mgemm3<HD, false, false, true, false, true, false, false>
            <<<GB, 256, 0, stream>>>(bufA, nullptr, w_conv + (size_t)l * HD * HD,
                                     conv_b + l * HD, ln_g + l * HD, ln_b + l * HD,
                                     nullptr, hbf, NN);
    }

    // --- graph mean pooling ---
    goff_kernel<<<(GG + 256) / 256, 256, 0, stream>>>(batchv, goff);
    pool_kernel<<<GG, 64, 0, stream>>>((const unsigned int*)hbf, goff, (unsigned int*)emb);

    // --- phys1: t1 = silu(hbf @ w_p1^T + b_p1) -> bufA ---
    mgemm3<HD, false, false, true, true, false, false, true>
        <<<GB, 256, 0, stream>>>(hbf, nullptr, w_p1, phys_b1, nullptr, nullptr,
                                 nullptr, bufA, NN);

    // --- fused tail: t2 = [hbf | t1] @ wf^T + biasf -> bufB (bf16) ---
    mgemm3<2 * HD, false, true, true, false, false, false, true>
        <<<GB, 256, 0, stream>>>(hbf, bufA, wf, biasf, nullptr, nullptr,
                                 nullptr, bufB, NN);

    // --- embp = emb @ w_h1b^T + b1 (per-graph, f32) ---
    mgemm3<HD, false, false, true, false, false, true, false>
        <<<GG / 128, 256, 0, stream>>>(emb, nullptr, w_h1b, head_b1, nullptr, nullptr,
                                       embp, nullptr, GG);

    // --- out = dot(silu(t2 + embp[batch]), w2) + b2 ---
    final_kernel<<<NN / 4, 256, 0, stream>>>(
        (const unsigned int*)bufB, (const float2*)embp, batchv, head_w2, head_b2, out);
}

// Round 7
// 660.188 us; speedup vs baseline: 1.2458x; 1.1811x over previous
//
#include <hip/hip_runtime.h>
#include <hip/hip_bf16.h>
#include <math.h>

// Problem constants (fixed-size problem)
#define NN      200000   // nodes
#define EE      600000   // directed edges
#define GG      8192     // graphs
#define DIN     64       // input dim
#define HD      128      // hidden dim
#define NL      4        // layers
#define LN_EPS  1e-5f

static constexpr int NB_SCAN = (NN + 255) / 256;   // 782 blocks for node scan

typedef __attribute__((ext_vector_type(8))) short short8;   // 8 bf16 (4 VGPRs)
typedef __attribute__((ext_vector_type(4))) float floatx4;  // MFMA accumulator

// bf16x2 <-> float2 (exact: bf16->f32 is a 16-bit shift)
__device__ inline float2 unpack_bf2(unsigned int p) {
    return make_float2(__uint_as_float(p << 16), __uint_as_float(p & 0xffff0000u));
}
__device__ inline unsigned int pack_bf2(float a, float b) {
    __hip_bfloat16 lo = __float2bfloat16(a);
    __hip_bfloat16 hi = __float2bfloat16(b);
    unsigned short ul = *reinterpret_cast<unsigned short*>(&lo);
    unsigned short uh = *reinterpret_cast<unsigned short*>(&hi);
    return (unsigned int)ul | ((unsigned int)uh << 16);
}
__device__ inline short bf16bits(float x) {
    __hip_bfloat16 t = __float2bfloat16(x);
    return *reinterpret_cast<short*>(&t);
}

// ---------------------------------------------------------------------------
// CSR build: degree histogram -> exclusive scan -> edge fill (with edge norm)
// ---------------------------------------------------------------------------
__global__ void hist_kernel(const int* __restrict__ dst, int* __restrict__ degi) {
    int e = blockIdx.x * 256 + threadIdx.x;
    if (e < EE) atomicAdd(&degi[dst[e]], 1);
}

__global__ void dis_kernel(const int* __restrict__ degi, float* __restrict__ dis) {
    int n = blockIdx.x * 256 + threadIdx.x;
    if (n < NN) dis[n] = rsqrtf((float)degi[n] + 1.0f);
}

__global__ void scan1_kernel(const int* __restrict__ degi, int* __restrict__ offs,
                             int* __restrict__ bsums) {
    __shared__ int s[256];
    int t = threadIdx.x;
    int i = blockIdx.x * 256 + t;
    int v = (i < NN) ? degi[i] : 0;
    s[t] = v;
    __syncthreads();
    for (int d = 1; d < 256; d <<= 1) {
        int add = (t >= d) ? s[t - d] : 0;
        __syncthreads();
        s[t] += add;
        __syncthreads();
    }
    if (i < NN) offs[i] = s[t] - v;
    if (t == 255) bsums[blockIdx.x] = s[255];
}

__global__ void scan2_kernel(int* __restrict__ bsums) {
    __shared__ int s[1024];
    int t = threadIdx.x;
    int v = (t < NB_SCAN) ? bsums[t] : 0;
    s[t] = v;
    __syncthreads();
    for (int d = 1; d < 1024; d <<= 1) {
        int add = (t >= d) ? s[t - d] : 0;
        __syncthreads();
        s[t] += add;
        __syncthreads();
    }
    if (t < NB_SCAN) bsums[t] = s[t] - v;
}

__global__ void scan3_kernel(int* __restrict__ offs, const int* __restrict__ bsums,
                             int* __restrict__ cursor) {
    int i = blockIdx.x * 256 + threadIdx.x;
    if (i < NN) {
        int v = offs[i] + bsums[blockIdx.x];
        offs[i]   = v;
        cursor[i] = v;
    } else if (i == NN) {
        offs[i] = EE;
    }
}

// csre[p] = {src, dis[src]*dis[dst]} -- per-edge norm precomputed
__global__ void fill_kernel(const int* __restrict__ src, const int* __restrict__ dst,
                            const float* __restrict__ dis,
                            int* __restrict__ cursor, int2* __restrict__ csre) {
    int e = blockIdx.x * 256 + threadIdx.x;
    if (e < EE) {
        int s = src[e], d = dst[e];
        int p = atomicAdd(&cursor[d], 1);
        csre[p] = make_int2(s, __float_as_int(dis[s] * dis[d]));
    }
}

// ---------------------------------------------------------------------------
// Weight conversion f32 -> bf16 (strided rows)
// ---------------------------------------------------------------------------
__global__ void cvt_kernel(const float* __restrict__ src, __hip_bfloat16* __restrict__ dst,
                           int rows, int rlen, int sstride) {
    int idx = blockIdx.x * 256 + threadIdx.x;
    if (idx >= rows * rlen) return;
    int r = idx / rlen, c = idx - r * rlen;
    dst[idx] = __float2bfloat16(src[(size_t)r * sstride + c]);
}

// ---------------------------------------------------------------------------
// Precompute fused tail weight: wf[i][0:128] = W1a[i][:],
// wf[i][128:256] = (W1a @ phys_w2)[i][:], biasf[i] = dot(W1a[i], phys_b2).
// head_w1 is [128][256]; W1a = cols 0..127. Block i (128 blocks), thread j.
// ---------------------------------------------------------------------------
__global__ __launch_bounds__(128)
void pm_kernel(const float* __restrict__ head_w1, const float* __restrict__ phys_w2,
               const float* __restrict__ phys_b2, __hip_bfloat16* __restrict__ wf,
               float* __restrict__ biasf)
{
    int i = blockIdx.x;
    int j = threadIdx.x;
    const float* w1a = head_w1 + (size_t)i * 256;
    wf[(size_t)i * 256 + j] = __float2bfloat16(w1a[j]);
    float m = 0.f;
    #pragma unroll 4
    for (int c = 0; c < 128; ++c) m += w1a[c] * phys_w2[(size_t)c * 128 + j];
    wf[(size_t)i * 256 + 128 + j] = __float2bfloat16(m);

    float t = w1a[j] * phys_b2[j];
    #pragma unroll
    for (int o = 32; o > 0; o >>= 1) t += __shfl_down(t, o);
    __shared__ float red[2];
    if ((j & 63) == 0) red[j >> 6] = t;
    __syncthreads();
    if (j == 0) biasf[i] = red[0] + red[1];
}

// ---------------------------------------------------------------------------
// MFMA GEMM, W staged to LDS in 128-wide chunks (1 or 2 stages), A loaded
// global->VGPR in fragment layout. C[M,128] = epilogue(A[M,K] @ W[128,K]^T).
// 256 threads = 4 waves; each wave owns 32 rows x 128 cols (2 row-blocks x
// 8 col-blocks of 16x16x32 MFMA). LDS pitch CW+8 -> 2-way bank pattern (free).
// CONCAT: K=256 with A = [A1 | A2] (two 128-wide bf16 buffers), 2 stages.
// LNRES: v=silu(acc+bias); LN over 128 cols (16-lane butterfly); bf16
// residual read-modify-write on Cb.
// ---------------------------------------------------------------------------
template<int K, bool AF32, bool CONCAT, bool BIAS, bool SILU, bool LNRES,
         bool WF32, bool WBF>
__global__ __launch_bounds__(256, 3)
void mgemm4(const void* __restrict__ A1vp, const void* __restrict__ A2vp,
            const __hip_bfloat16* __restrict__ W,
            const float* __restrict__ bias,
            const float* __restrict__ lng, const float* __restrict__ lnb,
            float* __restrict__ Cf, __hip_bfloat16* __restrict__ Cb, int M)
{
    constexpr int CW    = (K < 128) ? K : 128;   // stage chunk width (k)
    constexpr int NS    = K / CW;                // 1 or 2 stages
    constexpr int PITCH = CW + 8;                // shorts; 2-way banks = free
    __shared__ short Ws[128 * PITCH];

    const int tid  = threadIdx.x;
    const int wave = tid >> 6;
    const int lane = tid & 63;
    const int l15  = lane & 15;
    const int quad = lane >> 4;
    const int m0   = blockIdx.x * 128;

    int ridx0 = m0 + wave * 32 + l15;
    int ridx1 = ridx0 + 16;
    if (ridx0 >= M) ridx0 = M - 1;
    if (ridx1 >= M) ridx1 = M - 1;

    const __hip_bfloat16* A1  = (const __hip_bfloat16*)A1vp;
    const __hip_bfloat16* A2  = (const __hip_bfloat16*)A2vp;
    const float*          A1f = (const float*)A1vp;

    floatx4 acc[2][8];
    #pragma unroll
    for (int mi = 0; mi < 2; ++mi)
        #pragma unroll
        for (int ni = 0; ni < 8; ++ni) acc[mi][ni] = (floatx4)0.f;

    constexpr int NC = CW / 32;                  // k-chunks per stage
    constexpr int CH = CW / 8;                   // short8 chunks per W row

    #pragma unroll
    for (int s = 0; s < NS; ++s) {
        // ---- A fragments for this stage (issued before barrier: overlaps
        //      previous stage's MFMAs) ----
        short8 afr[2][NC];
        #pragma unroll
        for (int kc = 0; kc < NC; ++kc) {
            int ko = kc * 32 + quad * 8;
            if (CONCAT) {
                const __hip_bfloat16* src = (s == 0) ? A1 : A2;
                afr[0][kc] = *(const short8*)(src + (size_t)ridx0 * CW + ko);
                afr[1][kc] = *(const short8*)(src + (size_t)ridx1 * CW + ko);
            } else if (AF32) {
                const float* p0 = A1f + (size_t)ridx0 * K + ko;
                const float* p1 = A1f + (size_t)ridx1 * K + ko;
                float4 a0 = *(const float4*)p0, a1 = *(const float4*)(p0 + 4);
                float4 b0 = *(const float4*)p1, b1 = *(const float4*)(p1 + 4);
                float av[8] = {a0.x, a0.y, a0.z, a0.w, a1.x, a1.y, a1.z, a1.w};
                float bw[8] = {b0.x, b0.y, b0.z, b0.w, b1.x, b1.y, b1.z, b1.w};
                #pragma unroll
                for (int j = 0; j < 8; ++j) {
                    afr[0][kc][j] = bf16bits(av[j]);
                    afr[1][kc][j] = bf16bits(bw[j]);
                }
            } else {
                afr[0][kc] = *(const short8*)(A1 + (size_t)ridx0 * K + ko);
                afr[1][kc] = *(const short8*)(A1 + (size_t)ridx1 * K + ko);
            }
        }

        // ---- stage W chunk s into LDS ----
        if (s > 0) __syncthreads();              // previous stage's reads done
        #pragma unroll
        for (int it = 0; it < (128 * CH) / 256; ++it) {
            int idx = it * 256 + tid;
            int c   = idx / CH;
            int k8  = (idx - c * CH) * 8;
            short8 v = *(const short8*)(W + (size_t)c * K + s * CW + k8);
            *(short8*)&Ws[c * PITCH + k8] = v;
        }
        __syncthreads();

        // ---- MFMA over this stage's k-chunks ----
        #pragma unroll
        for (int kc = 0; kc < NC; ++kc) {
            int ko = kc * 32 + quad * 8;
            #pragma unroll
            for (int ni = 0; ni < 8; ++ni) {
                short8 b = *(const short8*)&Ws[(ni * 16 + l15) * PITCH + ko];
                acc[0][ni] = __builtin_amdgcn_mfma_f32_16x16x32_bf16(afr[0][kc], b, acc[0][ni], 0, 0, 0);
                acc[1][ni] = __builtin_amdgcn_mfma_f32_16x16x32_bf16(afr[1][kc], b, acc[1][ni], 0, 0, 0);
            }
        }
    }

    // epilogue preloads (col = ni*16 + l15)
    float bv[8], gv[8], lbv[8];
    #pragma unroll
    for (int ni = 0; ni < 8; ++ni) {
        int col = ni * 16 + l15;
        if (BIAS)   bv[ni]  = bias[col];
        if (LNRES) { gv[ni] = lng[col]; lbv[ni] = lnb[col]; }
    }

    #pragma unroll
    for (int mi = 0; mi < 2; ++mi) {
        #pragma unroll
        for (int r = 0; r < 4; ++r) {
            const int m = m0 + wave * 32 + mi * 16 + quad * 4 + r;
            if (LNRES) {
                float sv[8], p1 = 0.f, p2 = 0.f;
                #pragma unroll
                for (int ni = 0; ni < 8; ++ni) {
                    float v = acc[mi][ni][r] + bv[ni];
                    v = v / (1.f + __expf(-v));          // silu
                    sv[ni] = v; p1 += v; p2 += v * v;
                }
                #pragma unroll
                for (int o = 1; o < 16; o <<= 1) {       // 16-lane butterfly
                    p1 += __shfl_xor(p1, o);
                    p2 += __shfl_xor(p2, o);
                }
                float mu  = p1 * (1.f / 128.f);
                float var = p2 * (1.f / 128.f) - mu * mu;
                float rs  = rsqrtf(var + LN_EPS);
                if (m < M) {
                    #pragma unroll
                    for (int ni = 0; ni < 8; ++ni) {
                        int col = ni * 16 + l15;
                        float y  = (sv[ni] - mu) * rs * gv[ni] + lbv[ni];
                        float hn = __bfloat162float(Cb[(size_t)m * HD + col]) + y;
                        Cb[(size_t)m * HD + col] = __float2bfloat16(hn);
                    }
                }
            } else if (m < M) {
                #pragma unroll
                for (int ni = 0; ni < 8; ++ni) {
                    int col = ni * 16 + l15;
                    float v = acc[mi][ni][r];
                    if (BIAS) v += bv[ni];
                    if (SILU) v = v / (1.f + __expf(-v));
                    if (WF32) Cf[(size_t)m * HD + col] = v;
                    if (WBF)  Cb[(size_t)m * HD + col] = __float2bfloat16(v);
                }
            }
        }
    }
}

// ---------------------------------------------------------------------------
// Aggregation: 16 lanes per node (uint4 = 8 bf16 features/lane), 4 nodes per
// wave -> 4 independent edge streams per wave. x2 unroll inside each stream.
// agg[n] = self_n*h[n] + sum_e norm_e * h[src_e].
// ---------------------------------------------------------------------------
__global__ __launch_bounds__(256)
void agg_kernel(const uint4* __restrict__ hb4, const float* __restrict__ dis,
                const int* __restrict__ offs, const int2* __restrict__ csre,
                uint4* __restrict__ agg4)
{
    const int lane = threadIdx.x & 63;
    const int l16  = lane & 15;
    const int w    = (blockIdx.x * 256 + threadIdx.x) >> 6;
    const int n    = w * 4 + (lane >> 4);       // NN % 16 == 0 at grid level

    const float dn = dis[n];
    uint4 sp = hb4[(size_t)n * 16 + l16];
    float acc[8];
    {
        float s = dn * dn;
        float2 f0 = unpack_bf2(sp.x), f1 = unpack_bf2(sp.y);
        float2 f2 = unpack_bf2(sp.z), f3 = unpack_bf2(sp.w);
        acc[0] = f0.x * s; acc[1] = f0.y * s;
        acc[2] = f1.x * s; acc[3] = f1.y * s;
        acc[4] = f2.x * s; acc[5] = f2.y * s;
        acc[6] = f3.x * s; acc[7] = f3.y * s;
    }

    int e  = offs[n];
    int e1 = offs[n + 1];
    for (; e + 2 <= e1; e += 2) {
        int2 ea = csre[e];
        int2 eb = csre[e + 1];
        uint4 pa = hb4[(size_t)ea.x * 16 + l16];
        uint4 pb = hb4[(size_t)eb.x * 16 + l16];
        float wa = __int_as_float(ea.y);
        float wb = __int_as_float(eb.y);
        float2 a0 = unpack_bf2(pa.x), a1 = unpack_bf2(pa.y);
        float2 a2 = unpack_bf2(pa.z), a3 = unpack_bf2(pa.w);
        float2 b0 = unpack_bf2(pb.x), b1 = unpack_bf2(pb.y);
        float2 b2 = unpack_bf2(pb.z), b3 = unpack_bf2(pb.w);
        acc[0] += wa * a0.x + wb * b0.x; acc[1] += wa * a0.y + wb * b0.y;
        acc[2] += wa * a1.x + wb * b1.x; acc[3] += wa * a1.y + wb * b1.y;
        acc[4] += wa * a2.x + wb * b2.x; acc[5] += wa * a2.y + wb * b2.y;
        acc[6] += wa * a3.x + wb * b3.x; acc[7] += wa * a3.y + wb * b3.y;
    }
    if (e < e1) {
        int2 ea = csre[e];
        uint4 pa = hb4[(size_t)ea.x * 16 + l16];
        float wa = __int_as_float(ea.y);
        float2 a0 = unpack_bf2(pa.x), a1 = unpack_bf2(pa.y);
        float2 a2 = unpack_bf2(pa.z), a3 = unpack_bf2(pa.w);
        acc[0] += wa * a0.x; acc[1] += wa * a0.y;
        acc[2] += wa * a1.x; acc[3] += wa * a1.y;
        acc[4] += wa * a2.x; acc[5] += wa * a2.y;
        acc[6] += wa * a3.x; acc[7] += wa * a3.y;
    }

    uint4 o;
    o.x = pack_bf2(acc[0], acc[1]);
    o.y = pack_bf2(acc[2], acc[3]);
    o.z = pack_bf2(acc[4], acc[5]);
    o.w = pack_bf2(acc[6], acc[7]);
    agg4[(size_t)n * 16 + l16] = o;
}

// ---------------------------------------------------------------------------
// Graph pooling: offsets via binary search (batch_vec sorted), mean -> bf16.
// ---------------------------------------------------------------------------
__global__ void goff_kernel(const int* __restrict__ bv, int* __restrict__ goff) {
    int g = blockIdx.x * 256 + threadIdx.x;
    if (g > GG) return;
    int lo = 0, hi = NN;
    while (lo < hi) {
        int mid = (lo + hi) >> 1;
        if (bv[mid] < g) lo = mid + 1; else hi = mid;
    }
    goff[g] = lo;
}

__global__ __launch_bounds__(64)
void pool_kernel(const unsigned int* __restrict__ hu, const int* __restrict__ goff,
                 unsigned int* __restrict__ embu)
{
    int g = blockIdx.x;
    int f = threadIdx.x;          // 0..63
    int i0 = goff[g], i1 = goff[g + 1];
    float s0 = 0.f, s1 = 0.f;
    for (int i = i0; i < i1; ++i) {
        float2 v = unpack_bf2(hu[(size_t)i * 64 + f]);
        s0 += v.x; s1 += v.y;
    }
    float c = fmaxf((float)(i1 - i0), 1.f);
    embu[(size_t)g * 64 + f] = pack_bf2(s0 / c, s1 / c);
}

// ---------------------------------------------------------------------------
// Final head: out[n] = dot(silu(t2[n] + embp[batch[n]]), w2) + b2.
// One wave per node, 2 features per lane.
// ---------------------------------------------------------------------------
__global__ __launch_bounds__(256)
void final_kernel(const unsigned int* __restrict__ t2u, const float2* __restrict__ embp2,
                  const int* __restrict__ bv, const float* __restrict__ w2,
                  const float* __restrict__ b2, float* __restrict__ out)
{
    int gw   = (blockIdx.x * 256 + threadIdx.x) >> 6;
    int lane = threadIdx.x & 63;
    if (gw >= NN) return;
    int g = bv[gw];
    float2 t = unpack_bf2(t2u[(size_t)gw * 64 + lane]);
    float2 e = embp2[(size_t)g * 64 + lane];
    float v0 = t.x + e.x, v1 = t.y + e.y;
    v0 = v0 / (1.f + __expf(-v0));
    v1 = v1 / (1.f + __expf(-v1));
    float2 wv = *((const float2*)w2 + lane);
    float s = v0 * wv.x + v1 * wv.y;
    #pragma unroll
    for (int o = 32; o > 0; o >>= 1) s += __shfl_down(s, o);
    if (lane == 0) out[gw] = s + b2[0];
}

// ---------------------------------------------------------------------------
// Launcher
// ---------------------------------------------------------------------------
extern "C" void kernel_launch(void* const* d_in, const int* in_sizes, int n_in,
                              void* d_out, int out_size, void* d_ws, size_t ws_size,
                              hipStream_t stream)
{
    const float* x        = (const float*)d_in[0];
    const int*   eidx     = (const int*)d_in[1];
    const int*   batchv   = (const int*)d_in[2];
    const float* in_w     = (const float*)d_in[3];
    const float* in_b     = (const float*)d_in[4];
    const float* conv_w   = (const float*)d_in[5];
    const float* conv_b   = (const float*)d_in[6];
    const float* ln_g     = (const float*)d_in[7];
    const float* ln_b     = (const float*)d_in[8];
    const float* phys_w1  = (const float*)d_in[9];
    const float* phys_b1  = (const float*)d_in[10];
    const float* phys_w2  = (const float*)d_in[11];
    const float* phys_b2  = (const float*)d_in[12];
    const float* head_w1  = (const float*)d_in[13];
    const float* head_b1  = (const float*)d_in[14];
    const float* head_w2  = (const float*)d_in[15];
    const float* head_b2  = (const float*)d_in[16];
    float* out = (float*)d_out;

    const int* esrc = eidx;
    const int* edst = eidx + EE;

    // workspace layout (~170 MB)
    char* base = (char*)d_ws;
    size_t off = 0;
    auto alloc = [&](size_t bytes) {
        char* p = base + off;
        off = (off + bytes + 255) & ~(size_t)255;
        return p;
    };
    __hip_bfloat16* hbf    = (__hip_bfloat16*)alloc((size_t)NN * HD * 2);
    __hip_bfloat16* bufA   = (__hip_bfloat16*)alloc((size_t)NN * HD * 2);
    __hip_bfloat16* bufB   = (__hip_bfloat16*)alloc((size_t)NN * HD * 2);
    float*          dis    = (float*)alloc((size_t)NN * 4);
    int*            degi   = (int*)  alloc((size_t)NN * 4);
    int*            offs   = (int*)  alloc((size_t)(NN + 1) * 4);
    int*            cursor = (int*)  alloc((size_t)NN * 4);
    int2*           csre   = (int2*) alloc((size_t)EE * 8);
    __hip_bfloat16* emb    = (__hip_bfloat16*)alloc((size_t)GG * HD * 2);
    float*          embp   = (float*)alloc((size_t)GG * HD * 4);
    int*            goff   = (int*)  alloc((size_t)(GG + 1) * 4);
    int*            bsums  = (int*)  alloc(1024 * 4);
    __hip_bfloat16* w_in   = (__hip_bfloat16*)alloc(HD * DIN * 2);
    __hip_bfloat16* w_conv = (__hip_bfloat16*)alloc((size_t)NL * HD * HD * 2);
    __hip_bfloat16* w_p1   = (__hip_bfloat16*)alloc(HD * HD * 2);
    __hip_bfloat16* w_h1b  = (__hip_bfloat16*)alloc(HD * HD * 2);
    __hip_bfloat16* wf     = (__hip_bfloat16*)alloc(HD * 2 * HD * 2);
    float*          biasf  = (float*)alloc(HD * 4);
    (void)ws_size; (void)n_in; (void)in_sizes; (void)out_size;

    const int GB = (NN + 127) / 128;   // 1563 GEMM blocks

    // --- weight prep (tiny) ---
    cvt_kernel<<<(HD * DIN + 255) / 256, 256, 0, stream>>>(in_w, w_in, HD, DIN, DIN);
    cvt_kernel<<<(NL * HD * HD + 255) / 256, 256, 0, stream>>>(conv_w, w_conv, NL * HD, HD, HD);
    cvt_kernel<<<(HD * HD + 255) / 256, 256, 0, stream>>>(phys_w1, w_p1, HD, HD, HD);
    cvt_kernel<<<(HD * HD + 255) / 256, 256, 0, stream>>>(head_w1 + HD, w_h1b, HD, HD, 2 * HD);
    pm_kernel<<<HD, HD, 0, stream>>>(head_w1, phys_w2, phys_b2, wf, biasf);

    // --- CSR build ---
    hipMemsetAsync(degi, 0, (size_t)NN * 4, stream);
    hist_kernel<<<(EE + 255) / 256, 256, 0, stream>>>(edst, degi);
    dis_kernel<<<(NN + 255) / 256, 256, 0, stream>>>(degi, dis);
    scan1_kernel<<<NB_SCAN, 256, 0, stream>>>(degi, offs, bsums);
    scan2_kernel<<<1, 1024, 0, stream>>>(bsums);
    scan3_kernel<<<NB_SCAN, 256, 0, stream>>>(offs, bsums, cursor);
    fill_kernel<<<(EE + 255) / 256, 256, 0, stream>>>(esrc, edst, dis, cursor, csre);

    // --- input projection: hbf = x @ in_w.T + in_b ---
    mgemm4<DIN, true, false, true, false, false, false, true>
        <<<GB, 256, 0, stream>>>(x, nullptr, w_in, in_b, nullptr, nullptr,
                                 nullptr, hbf, NN);

    // --- GCN layers: agg first (linearity), then GEMM w/ fused SiLU+LN+bf16 residual ---
    for (int l = 0; l < NL; ++l) {
        agg_kernel<<<NN / 16, 256, 0, stream>>>(
            (const uint4*)hbf, dis, offs, csre, (uint4*)bufA);
        mgemm4<HD, false, false, true, false, true, false, false>
            <<<GB, 256, 0, stream>>>(bufA, nullptr, w_conv + (size_t)l * HD * HD,
                                     conv_b + l * HD, ln_g + l * HD, ln_b + l * HD,
                                     nullptr, hbf, NN);
    }

    // --- graph mean pooling ---
    goff_kernel<<<(GG + 256) / 256, 256, 0, stream>>>(batchv, goff);
    pool_kernel<<<GG, 64, 0, stream>>>((const unsigned int*)hbf, goff, (unsigned int*)emb);

    // --- phys1: t1 = silu(hbf @ w_p1^T + b_p1) -> bufA ---
    mgemm4<HD, false, false, true, true, false, false, true>
        <<<GB, 256, 0, stream>>>(hbf, nullptr, w_p1, phys_b1, nullptr, nullptr,
                                 nullptr, bufA, NN);

    // --- fused tail: t2 = [hbf | t1] @ wf^T + biasf -> bufB (bf16) ---
    mgemm4<2 * HD, false, true, true, false, false, false, true>
        <<<GB, 256, 0, stream>>>(hbf, bufA, wf, biasf, nullptr, nullptr,
                                 nullptr, bufB, NN);

    // --- embp = emb @ w_h1b^T + b1 (per-graph, f32) ---
    mgemm4<HD, false, false, true, false, false, true, false>
        <<<GG / 128, 256, 0, stream>>>(emb, nullptr, w_h1b, head_b1, nullptr, nullptr,
                                       embp, nullptr, GG);

    // --- out = dot(silu(t2 + embp[batch]), w2) + b2 ---
    final_kernel<<<NN / 4, 256, 0, stream>>>(
        (const unsigned int*)bufB, (const float2*)embp, batchv, head_w2, head_b2, out);
}

// Round 8
// 635.315 us; speedup vs baseline: 1.2945x; 1.0392x over previous
//
#include <hip/hip_runtime.h>
#include <hip/hip_bf16.h>
#include <math.h>

// Problem constants (fixed-size problem)
#define NN      200000   // nodes
#define EE      600000   // directed edges
#define GG      8192     // graphs
#define DIN     64       // input dim
#define HD      128      // hidden dim
#define NL      4        // layers
#define LN_EPS  1e-5f

static constexpr int NB_SCAN = (NN + 255) / 256;   // 782 blocks for node scan

typedef __attribute__((ext_vector_type(8))) short short8;   // 8 bf16 (4 VGPRs)
typedef __attribute__((ext_vector_type(4))) float floatx4;  // MFMA accumulator

// bf16x2 <-> float2 (exact: bf16->f32 is a 16-bit shift)
__device__ inline float2 unpack_bf2(unsigned int p) {
    return make_float2(__uint_as_float(p << 16), __uint_as_float(p & 0xffff0000u));
}
__device__ inline unsigned int pack_bf2(float a, float b) {
    __hip_bfloat16 lo = __float2bfloat16(a);
    __hip_bfloat16 hi = __float2bfloat16(b);
    unsigned short ul = *reinterpret_cast<unsigned short*>(&lo);
    unsigned short uh = *reinterpret_cast<unsigned short*>(&hi);
    return (unsigned int)ul | ((unsigned int)uh << 16);
}
__device__ inline short bf16bits(float x) {
    __hip_bfloat16 t = __float2bfloat16(x);
    return *reinterpret_cast<short*>(&t);
}
__device__ inline float silu(float v) { return v / (1.f + __expf(-v)); }

// fragment-layout index for W[c][k] with inner dim K:
// slot = ((k/32)*8 + c/16)*64 + ((k>>3)&3)*16 + (c&15), elem j = k&7
__device__ __host__ inline size_t fragidx(int c, int k) {
    return (size_t)((((k >> 5) * 8 + (c >> 4)) * 64 + ((k >> 3) & 3) * 16 + (c & 15)) * 8
                    + (k & 7));
}

// ---------------------------------------------------------------------------
// CSR build: degree histogram -> exclusive scan -> edge fill (with edge norm)
// ---------------------------------------------------------------------------
__global__ void hist_kernel(const int* __restrict__ dst, int* __restrict__ degi) {
    int e = blockIdx.x * 256 + threadIdx.x;
    if (e < EE) atomicAdd(&degi[dst[e]], 1);
}

__global__ void dis_kernel(const int* __restrict__ degi, float* __restrict__ dis) {
    int n = blockIdx.x * 256 + threadIdx.x;
    if (n < NN) dis[n] = rsqrtf((float)degi[n] + 1.0f);
}

__global__ void scan1_kernel(const int* __restrict__ degi, int* __restrict__ offs,
                             int* __restrict__ bsums) {
    __shared__ int s[256];
    int t = threadIdx.x;
    int i = blockIdx.x * 256 + t;
    int v = (i < NN) ? degi[i] : 0;
    s[t] = v;
    __syncthreads();
    for (int d = 1; d < 256; d <<= 1) {
        int add = (t >= d) ? s[t - d] : 0;
        __syncthreads();
        s[t] += add;
        __syncthreads();
    }
    if (i < NN) offs[i] = s[t] - v;
    if (t == 255) bsums[blockIdx.x] = s[255];
}

__global__ void scan2_kernel(int* __restrict__ bsums) {
    __shared__ int s[1024];
    int t = threadIdx.x;
    int v = (t < NB_SCAN) ? bsums[t] : 0;
    s[t] = v;
    __syncthreads();
    for (int d = 1; d < 1024; d <<= 1) {
        int add = (t >= d) ? s[t - d] : 0;
        __syncthreads();
        s[t] += add;
        __syncthreads();
    }
    if (t < NB_SCAN) bsums[t] = s[t] - v;
}

__global__ void scan3_kernel(int* __restrict__ offs, const int* __restrict__ bsums,
                             int* __restrict__ cursor) {
    int i = blockIdx.x * 256 + threadIdx.x;
    if (i < NN) {
        int v = offs[i] + bsums[blockIdx.x];
        offs[i]   = v;
        cursor[i] = v;
    } else if (i == NN) {
        offs[i] = EE;
    }
}

// csre[p] = {src, dis[src]*dis[dst]} -- per-edge norm precomputed
__global__ void fill_kernel(const int* __restrict__ src, const int* __restrict__ dst,
                            const float* __restrict__ dis,
                            int* __restrict__ cursor, int2* __restrict__ csre) {
    int e = blockIdx.x * 256 + threadIdx.x;
    if (e < EE) {
        int s = src[e], d = dst[e];
        int p = atomicAdd(&cursor[d], 1);
        csre[p] = make_int2(s, __float_as_int(dis[s] * dis[d]));
    }
}

// ---------------------------------------------------------------------------
// Weight conversion f32 -> bf16 FRAGMENT layout. src rows are the out-cols c
// (global row index = idx/K, row stride sstride); nmat matrices of 128 rows.
// ---------------------------------------------------------------------------
__global__ void cvtf_kernel(const float* __restrict__ src, __hip_bfloat16* __restrict__ dst,
                            int K, int sstride, int total) {
    int idx = blockIdx.x * 256 + threadIdx.x;
    if (idx >= total) return;
    int cg = idx / K;              // global out-col index (incl. matrix)
    int k  = idx - cg * K;
    int mat = cg >> 7;
    int c   = cg & 127;
    float v = src[(size_t)cg * sstride + k];
    dst[(size_t)mat * 128 * K + fragidx(c, k)] = __float2bfloat16(v);
}

// ---------------------------------------------------------------------------
// Fused tail weight (fragment layout, K=256): wf(c, 0:128) = W1a[c][:],
// wf(c, 128:256) = (W1a @ phys_w2)[c][:], biasf[c] = dot(W1a[c], phys_b2).
// ---------------------------------------------------------------------------
__global__ __launch_bounds__(128)
void pm_kernel(const float* __restrict__ head_w1, const float* __restrict__ phys_w2,
               const float* __restrict__ phys_b2, __hip_bfloat16* __restrict__ wf,
               float* __restrict__ biasf)
{
    int i = blockIdx.x;            // out col c
    int j = threadIdx.x;           // 0..127
    const float* w1a = head_w1 + (size_t)i * 256;
    wf[fragidx(i, j)] = __float2bfloat16(w1a[j]);
    float m = 0.f;
    #pragma unroll 4
    for (int c = 0; c < 128; ++c) m += w1a[c] * phys_w2[(size_t)c * 128 + j];
    wf[fragidx(i, 128 + j)] = __float2bfloat16(m);

    float t = w1a[j] * phys_b2[j];
    #pragma unroll
    for (int o = 32; o > 0; o >>= 1) t += __shfl_down(t, o);
    __shared__ float red[2];
    if ((j & 63) == 0) red[j >> 6] = t;
    __syncthreads();
    if (j == 0) biasf[i] = red[0] + red[1];
}

// ---------------------------------------------------------------------------
// Simple MFMA GEMM, zero LDS, W in fragment layout (coalesced L2-hot loads).
// C[M,128] = act(A[M,K] @ W^T (+bias)). 4 waves x (32 rows x 128 cols).
// ---------------------------------------------------------------------------
template<int K, bool AF32, bool BIAS, bool SILU_, bool WF32, bool WBF>
__global__ __launch_bounds__(256, 4)
void mgemm5(const void* __restrict__ Avp, const __hip_bfloat16* __restrict__ wfrag,
            const float* __restrict__ bias,
            float* __restrict__ Cf, __hip_bfloat16* __restrict__ Cb, int M)
{
    const int tid  = threadIdx.x;
    const int wave = tid >> 6;
    const int lane = tid & 63;
    const int l15  = lane & 15;
    const int quad = lane >> 4;
    const int m0   = blockIdx.x * 128;

    int ridx0 = m0 + wave * 32 + l15;
    int ridx1 = ridx0 + 16;
    if (ridx0 >= M) ridx0 = M - 1;
    if (ridx1 >= M) ridx1 = M - 1;

    constexpr int NC = K / 32;
    short8 a0[NC], a1[NC];
    const __hip_bfloat16* Ab = (const __hip_bfloat16*)Avp;
    const float*          Af = (const float*)Avp;
    #pragma unroll
    for (int kc = 0; kc < NC; ++kc) {
        int ko = kc * 32 + quad * 8;
        if (AF32) {
            const float* p0 = Af + (size_t)ridx0 * K + ko;
            const float* p1 = Af + (size_t)ridx1 * K + ko;
            float4 x0 = *(const float4*)p0, x1 = *(const float4*)(p0 + 4);
            float4 y0 = *(const float4*)p1, y1 = *(const float4*)(p1 + 4);
            float xv[8] = {x0.x, x0.y, x0.z, x0.w, x1.x, x1.y, x1.z, x1.w};
            float yv[8] = {y0.x, y0.y, y0.z, y0.w, y1.x, y1.y, y1.z, y1.w};
            #pragma unroll
            for (int j = 0; j < 8; ++j) { a0[kc][j] = bf16bits(xv[j]); a1[kc][j] = bf16bits(yv[j]); }
        } else {
            a0[kc] = *(const short8*)(Ab + (size_t)ridx0 * K + ko);
            a1[kc] = *(const short8*)(Ab + (size_t)ridx1 * K + ko);
        }
    }

    floatx4 acc[2][8];
    #pragma unroll
    for (int mi = 0; mi < 2; ++mi)
        #pragma unroll
        for (int ni = 0; ni < 8; ++ni) acc[mi][ni] = (floatx4)0.f;

    const short* Wp = (const short*)wfrag;
    #pragma unroll
    for (int kc = 0; kc < NC; ++kc) {
        #pragma unroll
        for (int ni = 0; ni < 8; ++ni) {
            short8 b = *(const short8*)(Wp + (size_t)((kc * 8 + ni) * 64 + lane) * 8);
            acc[0][ni] = __builtin_amdgcn_mfma_f32_16x16x32_bf16(a0[kc], b, acc[0][ni], 0, 0, 0);
            acc[1][ni] = __builtin_amdgcn_mfma_f32_16x16x32_bf16(a1[kc], b, acc[1][ni], 0, 0, 0);
        }
    }

    float bv[8];
    #pragma unroll
    for (int ni = 0; ni < 8; ++ni) if (BIAS) bv[ni] = bias[ni * 16 + l15];

    #pragma unroll
    for (int mi = 0; mi < 2; ++mi) {
        #pragma unroll
        for (int r = 0; r < 4; ++r) {
            const int m = m0 + wave * 32 + mi * 16 + quad * 4 + r;
            if (m < M) {
                #pragma unroll
                for (int ni = 0; ni < 8; ++ni) {
                    int col = ni * 16 + l15;
                    float v = acc[mi][ni][r];
                    if (BIAS)  v += bv[ni];
                    if (SILU_) v = silu(v);
                    if (WF32)  Cf[(size_t)m * HD + col] = v;
                    if (WBF)   Cb[(size_t)m * HD + col] = __float2bfloat16(v);
                }
            }
        }
    }
}

// ---------------------------------------------------------------------------
// FUSED GCN layer: per block of 128 nodes --
// phase 1: aggregate h_in rows (self + edges) into LDS (bf16, pitch 136);
// phase 2: MFMA agg @ conv_w^T (W fragment-layout from global, no staging);
// epilogue: h_out = h_in + LN(silu(acc + cb)). Ping-pong h buffers (no race).
// ---------------------------------------------------------------------------
__global__ __launch_bounds__(256, 4)
void conv_fused(const __hip_bfloat16* __restrict__ hin,
                const __hip_bfloat16* __restrict__ wfrag,
                const float* __restrict__ dis,
                const int* __restrict__ offs, const int2* __restrict__ csre,
                const float* __restrict__ cb, const float* __restrict__ lng,
                const float* __restrict__ lnb,
                __hip_bfloat16* __restrict__ hout, int M)
{
    __shared__ short As[128 * 136];         // 34816 B, pitch 136 -> even banks
    const int tid  = threadIdx.x;
    const int wave = tid >> 6;
    const int lane = tid & 63;
    const int l15  = lane & 15;
    const int quad = lane >> 4;
    const int m0   = blockIdx.x * 128;

    // ---- phase 1: aggregation into LDS ----
    {
        const int l16 = tid & 15;           // feature chunk (8 bf16 = uint4)
        const int ns  = tid >> 4;           // node stream 0..15
        const uint4* h4 = (const uint4*)hin;
        for (int it = 0; it < 8; ++it) {
            int nl = it * 16 + ns;          // local node 0..127
            int n  = m0 + nl;
            float acc[8];
            if (n < M) {
                float dn = dis[n];
                uint4 sp = h4[(size_t)n * 16 + l16];
                float s = dn * dn;
                float2 f0 = unpack_bf2(sp.x), f1 = unpack_bf2(sp.y);
                float2 f2 = unpack_bf2(sp.z), f3 = unpack_bf2(sp.w);
                acc[0] = f0.x * s; acc[1] = f0.y * s;
                acc[2] = f1.x * s; acc[3] = f1.y * s;
                acc[4] = f2.x * s; acc[5] = f2.y * s;
                acc[6] = f3.x * s; acc[7] = f3.y * s;
                int e  = offs[n];
                int e1 = offs[n + 1];
                for (; e + 2 <= e1; e += 2) {
                    int2 ea = csre[e];
                    int2 eb = csre[e + 1];
                    uint4 pa = h4[(size_t)ea.x * 16 + l16];
                    uint4 pb = h4[(size_t)eb.x * 16 + l16];
                    float wa = __int_as_float(ea.y);
                    float wb = __int_as_float(eb.y);
                    float2 A0 = unpack_bf2(pa.x), A1 = unpack_bf2(pa.y);
                    float2 A2 = unpack_bf2(pa.z), A3 = unpack_bf2(pa.w);
                    float2 B0 = unpack_bf2(pb.x), B1 = unpack_bf2(pb.y);
                    float2 B2 = unpack_bf2(pb.z), B3 = unpack_bf2(pb.w);
                    acc[0] += wa * A0.x + wb * B0.x; acc[1] += wa * A0.y + wb * B0.y;
                    acc[2] += wa * A1.x + wb * B1.x; acc[3] += wa * A1.y + wb * B1.y;
                    acc[4] += wa * A2.x + wb * B2.x; acc[5] += wa * A2.y + wb * B2.y;
                    acc[6] += wa * A3.x + wb * B3.x; acc[7] += wa * A3.y + wb * B3.y;
                }
                if (e < e1) {
                    int2 ea = csre[e];
                    uint4 pa = h4[(size_t)ea.x * 16 + l16];
                    float wa = __int_as_float(ea.y);
                    float2 A0 = unpack_bf2(pa.x), A1 = unpack_bf2(pa.y);
                    float2 A2 = unpack_bf2(pa.z), A3 = unpack_bf2(pa.w);
                    acc[0] += wa * A0.x; acc[1] += wa * A0.y;
                    acc[2] += wa * A1.x; acc[3] += wa * A1.y;
                    acc[4] += wa * A2.x; acc[5] += wa * A2.y;
                    acc[6] += wa * A3.x; acc[7] += wa * A3.y;
                }
            } else {
                #pragma unroll
                for (int j = 0; j < 8; ++j) acc[j] = 0.f;
            }
            uint4 o;
            o.x = pack_bf2(acc[0], acc[1]);
            o.y = pack_bf2(acc[2], acc[3]);
            o.z = pack_bf2(acc[4], acc[5]);
            o.w = pack_bf2(acc[6], acc[7]);
            *(uint4*)&As[nl * 136 + l16 * 8] = o;
        }
    }
    __syncthreads();

    // ---- phase 2: MFMA from LDS A, fragment-layout W from global ----
    floatx4 acc[2][8];
    #pragma unroll
    for (int mi = 0; mi < 2; ++mi)
        #pragma unroll
        for (int ni = 0; ni < 8; ++ni) acc[mi][ni] = (floatx4)0.f;

    const short* Wp = (const short*)wfrag;
    #pragma unroll
    for (int kc = 0; kc < 4; ++kc) {
        int ko = kc * 32 + quad * 8;
        short8 fa0 = *(const short8*)&As[(wave * 32 + l15) * 136 + ko];
        short8 fa1 = *(const short8*)&As[(wave * 32 + 16 + l15) * 136 + ko];
        #pragma unroll
        for (int ni = 0; ni < 8; ++ni) {
            short8 b = *(const short8*)(Wp + (size_t)((kc * 8 + ni) * 64 + lane) * 8);
            acc[0][ni] = __builtin_amdgcn_mfma_f32_16x16x32_bf16(fa0, b, acc[0][ni], 0, 0, 0);
            acc[1][ni] = __builtin_amdgcn_mfma_f32_16x16x32_bf16(fa1, b, acc[1][ni], 0, 0, 0);
        }
    }

    // ---- epilogue: SiLU + LN + residual (read hin, write hout) ----
    float bv[8], gv[8], lbv[8];
    #pragma unroll
    for (int ni = 0; ni < 8; ++ni) {
        int col = ni * 16 + l15;
        bv[ni]  = cb[col];
        gv[ni]  = lng[col];
        lbv[ni] = lnb[col];
    }
    #pragma unroll
    for (int mi = 0; mi < 2; ++mi) {
        #pragma unroll
        for (int r = 0; r < 4; ++r) {
            const int m = m0 + wave * 32 + mi * 16 + quad * 4 + r;
            float sv[8], p1 = 0.f, p2 = 0.f;
            #pragma unroll
            for (int ni = 0; ni < 8; ++ni) {
                float v = silu(acc[mi][ni][r] + bv[ni]);
                sv[ni] = v; p1 += v; p2 += v * v;
            }
            #pragma unroll
            for (int o = 1; o < 16; o <<= 1) {
                p1 += __shfl_xor(p1, o);
                p2 += __shfl_xor(p2, o);
            }
            float mu  = p1 * (1.f / 128.f);
            float var = p2 * (1.f / 128.f) - mu * mu;
            float rs  = rsqrtf(var + LN_EPS);
            if (m < M) {
                #pragma unroll
                for (int ni = 0; ni < 8; ++ni) {
                    int col = ni * 16 + l15;
                    float y  = (sv[ni] - mu) * rs * gv[ni] + lbv[ni];
                    float hn = __bfloat162float(hin[(size_t)m * HD + col]) + y;
                    hout[(size_t)m * HD + col] = __float2bfloat16(hn);
                }
            }
        }
    }
}

// ---------------------------------------------------------------------------
// FUSED tail: phase 1: t1 = silu(h @ w_p1^T + b1) into LDS (h frags kept in
// regs); phase 2: t2 = [h | t1] @ wf^T + biasf; epilogue: out = dot(silu(t2 +
// embp[batch]), w2) + b2.
// ---------------------------------------------------------------------------
__global__ __launch_bounds__(256, 3)
void tail_fused(const __hip_bfloat16* __restrict__ hbf,
                const __hip_bfloat16* __restrict__ wp1f, const float* __restrict__ pb1,
                const __hip_bfloat16* __restrict__ wff,  const float* __restrict__ biasf,
                const float* __restrict__ embp, const int* __restrict__ bv,
                const float* __restrict__ w2, const float* __restrict__ b2,
                float* __restrict__ out, int M)
{
    __shared__ short T1[128 * 136];
    const int tid  = threadIdx.x;
    const int wave = tid >> 6;
    const int lane = tid & 63;
    const int l15  = lane & 15;
    const int quad = lane >> 4;
    const int m0   = blockIdx.x * 128;

    int ridx0 = m0 + wave * 32 + l15;
    int ridx1 = ridx0 + 16;
    if (ridx0 >= M) ridx0 = M - 1;
    if (ridx1 >= M) ridx1 = M - 1;

    // h fragments (kept for phase 2)
    short8 ah0[4], ah1[4];
    #pragma unroll
    for (int kc = 0; kc < 4; ++kc) {
        int ko = kc * 32 + quad * 8;
        ah0[kc] = *(const short8*)(hbf + (size_t)ridx0 * HD + ko);
        ah1[kc] = *(const short8*)(hbf + (size_t)ridx1 * HD + ko);
    }

    // ---- phase 1: t1 tile ----
    {
        floatx4 a1[2][8];
        #pragma unroll
        for (int mi = 0; mi < 2; ++mi)
            #pragma unroll
            for (int ni = 0; ni < 8; ++ni) a1[mi][ni] = (floatx4)0.f;
        const short* Wp = (const short*)wp1f;
        #pragma unroll
        for (int kc = 0; kc < 4; ++kc) {
            #pragma unroll
            for (int ni = 0; ni < 8; ++ni) {
                short8 b = *(const short8*)(Wp + (size_t)((kc * 8 + ni) * 64 + lane) * 8);
                a1[0][ni] = __builtin_amdgcn_mfma_f32_16x16x32_bf16(ah0[kc], b, a1[0][ni], 0, 0, 0);
                a1[1][ni] = __builtin_amdgcn_mfma_f32_16x16x32_bf16(ah1[kc], b, a1[1][ni], 0, 0, 0);
            }
        }
        float pbv[8];
        #pragma unroll
        for (int ni = 0; ni < 8; ++ni) pbv[ni] = pb1[ni * 16 + l15];
        #pragma unroll
        for (int mi = 0; mi < 2; ++mi) {
            #pragma unroll
            for (int r = 0; r < 4; ++r) {
                int ml = wave * 32 + mi * 16 + quad * 4 + r;   // local row
                #pragma unroll
                for (int ni = 0; ni < 8; ++ni) {
                    float v = silu(a1[mi][ni][r] + pbv[ni]);
                    T1[ml * 136 + ni * 16 + l15] = bf16bits(v);
                }
            }
        }
    }
    __syncthreads();

    // ---- phase 2: t2 = [h | t1] @ wf^T ----
    floatx4 acc[2][8];
    #pragma unroll
    for (int mi = 0; mi < 2; ++mi)
        #pragma unroll
        for (int ni = 0; ni < 8; ++ni) acc[mi][ni] = (floatx4)0.f;

    const short* Wf = (const short*)wff;
    #pragma unroll
    for (int kc = 0; kc < 4; ++kc) {              // k = 0..127 : h part (regs)
        #pragma unroll
        for (int ni = 0; ni < 8; ++ni) {
            short8 b = *(const short8*)(Wf + (size_t)((kc * 8 + ni) * 64 + lane) * 8);
            acc[0][ni] = __builtin_amdgcn_mfma_f32_16x16x32_bf16(ah0[kc], b, acc[0][ni], 0, 0, 0);
            acc[1][ni] = __builtin_amdgcn_mfma_f32_16x16x32_bf16(ah1[kc], b, acc[1][ni], 0, 0, 0);
        }
    }
    #pragma unroll
    for (int kc = 4; kc < 8; ++kc) {              // k = 128..255 : t1 part (LDS)
        int ko = (kc - 4) * 32 + quad * 8;
        short8 ta0 = *(const short8*)&T1[(wave * 32 + l15) * 136 + ko];
        short8 ta1 = *(const short8*)&T1[(wave * 32 + 16 + l15) * 136 + ko];
        #pragma unroll
        for (int ni = 0; ni < 8; ++ni) {
            short8 b = *(const short8*)(Wf + (size_t)((kc * 8 + ni) * 64 + lane) * 8);
            acc[0][ni] = __builtin_amdgcn_mfma_f32_16x16x32_bf16(ta0, b, acc[0][ni], 0, 0, 0);
            acc[1][ni] = __builtin_amdgcn_mfma_f32_16x16x32_bf16(ta1, b, acc[1][ni], 0, 0, 0);
        }
    }

    // ---- epilogue: silu(t2 + embp[batch]) . w2 + b2 -> out ----
    float bfv[8], w2v[8];
    #pragma unroll
    for (int ni = 0; ni < 8; ++ni) {
        int col = ni * 16 + l15;
        bfv[ni] = biasf[col];
        w2v[ni] = w2[col];
    }
    const float b2v = b2[0];
    #pragma unroll
    for (int mi = 0; mi < 2; ++mi) {
        #pragma unroll
        for (int r = 0; r < 4; ++r) {
            const int m = m0 + wave * 32 + mi * 16 + quad * 4 + r;
            if (m >= M) continue;
            int g = bv[m];
            float p = 0.f;
            #pragma unroll
            for (int ni = 0; ni < 8; ++ni) {
                int col = ni * 16 + l15;
                float v = acc[mi][ni][r] + bfv[ni] + embp[(size_t)g * HD + col];
                p += silu(v) * w2v[ni];
            }
            #pragma unroll
            for (int o = 1; o < 16; o <<= 1) p += __shfl_xor(p, o);
            if (l15 == 0) out[m] = p + b2v;
        }
    }
}

// ---------------------------------------------------------------------------
// Graph pooling: offsets via binary search (batch_vec sorted), mean -> bf16.
// ---------------------------------------------------------------------------
__global__ void goff_kernel(const int* __restrict__ bv, int* __restrict__ goff) {
    int g = blockIdx.x * 256 + threadIdx.x;
    if (g > GG) return;
    int lo = 0, hi = NN;
    while (lo < hi) {
        int mid = (lo + hi) >> 1;
        if (bv[mid] < g) lo = mid + 1; else hi = mid;
    }
    goff[g] = lo;
}

__global__ __launch_bounds__(64)
void pool_kernel(const unsigned int* __restrict__ hu, const int* __restrict__ goff,
                 unsigned int* __restrict__ embu)
{
    int g = blockIdx.x;
    int f = threadIdx.x;          // 0..63
    int i0 = goff[g], i1 = goff[g + 1];
    float s0 = 0.f, s1 = 0.f;
    for (int i = i0; i < i1; ++i) {
        float2 v = unpack_bf2(hu[(size_t)i * 64 + f]);
        s0 += v.x; s1 += v.y;
    }
    float c = fmaxf((float)(i1 - i0), 1.f);
    embu[(size_t)g * 64 + f] = pack_bf2(s0 / c, s1 / c);
}

// ---------------------------------------------------------------------------
// Launcher
// ---------------------------------------------------------------------------
extern "C" void kernel_launch(void* const* d_in, const int* in_sizes, int n_in,
                              void* d_out, int out_size, void* d_ws, size_t ws_size,
                              hipStream_t stream)
{
    const float* x        = (const float*)d_in[0];
    const int*   eidx     = (const int*)d_in[1];
    const int*   batchv   = (const int*)d_in[2];
    const float* in_w     = (const float*)d_in[3];
    const float* in_b     = (const float*)d_in[4];
    const float* conv_w   = (const float*)d_in[5];
    const float* conv_b   = (const float*)d_in[6];
    const float* ln_g     = (const float*)d_in[7];
    const float* ln_b     = (const float*)d_in[8];
    const float* phys_w1  = (const float*)d_in[9];
    const float* phys_b1  = (const float*)d_in[10];
    const float* phys_w2  = (const float*)d_in[11];
    const float* phys_b2  = (const float*)d_in[12];
    const float* head_w1  = (const float*)d_in[13];
    const float* head_b1  = (const float*)d_in[14];
    const float* head_w2  = (const float*)d_in[15];
    const float* head_b2  = (const float*)d_in[16];
    float* out = (float*)d_out;

    const int* esrc = eidx;
    const int* edst = eidx + EE;

    // workspace layout (~130 MB)
    char* base = (char*)d_ws;
    size_t off = 0;
    auto alloc = [&](size_t bytes) {
        char* p = base + off;
        off = (off + bytes + 255) & ~(size_t)255;
        return p;
    };
    __hip_bfloat16* h0     = (__hip_bfloat16*)alloc((size_t)NN * HD * 2);
    __hip_bfloat16* h1     = (__hip_bfloat16*)alloc((size_t)NN * HD * 2);
    float*          dis    = (float*)alloc((size_t)NN * 4);
    int*            degi   = (int*)  alloc((size_t)NN * 4);
    int*            offs   = (int*)  alloc((size_t)(NN + 1) * 4);
    int*            cursor = (int*)  alloc((size_t)NN * 4);
    int2*           csre   = (int2*) alloc((size_t)EE * 8);
    __hip_bfloat16* emb    = (__hip_bfloat16*)alloc((size_t)GG * HD * 2);
    float*          embp   = (float*)alloc((size_t)GG * HD * 4);
    int*            goff   = (int*)  alloc((size_t)(GG + 1) * 4);
    int*            bsums  = (int*)  alloc(1024 * 4);
    __hip_bfloat16* w_in   = (__hip_bfloat16*)alloc(HD * DIN * 2);
    __hip_bfloat16* w_conv = (__hip_bfloat16*)alloc((size_t)NL * HD * HD * 2);
    __hip_bfloat16* w_p1   = (__hip_bfloat16*)alloc(HD * HD * 2);
    __hip_bfloat16* w_h1b  = (__hip_bfloat16*)alloc(HD * HD * 2);
    __hip_bfloat16* wf     = (__hip_bfloat16*)alloc(HD * 2 * HD * 2);
    float*          biasf  = (float*)alloc(HD * 4);
    (void)ws_size; (void)n_in; (void)in_sizes; (void)out_size;

    const int GB = (NN + 127) / 128;   // 1563 blocks

    // --- weight prep: fragment layouts (tiny) ---
    cvtf_kernel<<<(HD * DIN + 255) / 256, 256, 0, stream>>>(in_w, w_in, DIN, DIN, HD * DIN);
    cvtf_kernel<<<(NL * HD * HD + 255) / 256, 256, 0, stream>>>(conv_w, w_conv, HD, HD, NL * HD * HD);
    cvtf_kernel<<<(HD * HD + 255) / 256, 256, 0, stream>>>(phys_w1, w_p1, HD, HD, HD * HD);
    cvtf_kernel<<<(HD * HD + 255) / 256, 256, 0, stream>>>(head_w1 + HD, w_h1b, HD, 2 * HD, HD * HD);
    pm_kernel<<<HD, HD, 0, stream>>>(head_w1, phys_w2, phys_b2, wf, biasf);

    // --- CSR build ---
    hipMemsetAsync(degi, 0, (size_t)NN * 4, stream);
    hist_kernel<<<(EE + 255) / 256, 256, 0, stream>>>(edst, degi);
    dis_kernel<<<(NN + 255) / 256, 256, 0, stream>>>(degi, dis);
    scan1_kernel<<<NB_SCAN, 256, 0, stream>>>(degi, offs, bsums);
    scan2_kernel<<<1, 1024, 0, stream>>>(bsums);
    scan3_kernel<<<NB_SCAN, 256, 0, stream>>>(offs, bsums, cursor);
    fill_kernel<<<(EE + 255) / 256, 256, 0, stream>>>(esrc, edst, dis, cursor, csre);

    // --- input projection: h0 = x @ in_w^T + in_b ---
    mgemm5<DIN, true, true, false, false, true><<<GB, 256, 0, stream>>>(
        x, w_in, in_b, nullptr, h0, NN);

    // --- GCN layers (fused agg + conv + SiLU + LN + residual, ping-pong) ---
    for (int l = 0; l < NL; ++l) {
        const __hip_bfloat16* hin  = (l & 1) ? h1 : h0;
        __hip_bfloat16*       hout = (l & 1) ? h0 : h1;
        conv_fused<<<GB, 256, 0, stream>>>(
            hin, w_conv + (size_t)l * HD * HD, dis, offs, csre,
            conv_b + l * HD, ln_g + l * HD, ln_b + l * HD, hout, NN);
    }
    // after 4 layers final h is in h0

    // --- graph mean pooling + per-graph head projection ---
    goff_kernel<<<(GG + 256) / 256, 256, 0, stream>>>(batchv, goff);
    pool_kernel<<<GG, 64, 0, stream>>>((const unsigned int*)h0, goff, (unsigned int*)emb);
    mgemm5<HD, false, true, false, true, false><<<GG / 128, 256, 0, stream>>>(
        emb, w_h1b, head_b1, embp, nullptr, GG);

    // --- fused phys MLP + head + output dot ---
    tail_fused<<<GB, 256, 0, stream>>>(
        h0, w_p1, phys_b1, wf, biasf, embp, batchv, head_w2, head_b2, out, NN);
}

// Round 9
// 626.437 us; speedup vs baseline: 1.3129x; 1.0142x over previous
//
#include <hip/hip_runtime.h>
#include <hip/hip_bf16.h>
#include <math.h>

// Problem constants (fixed-size problem)
#define NN      200000   // nodes
#define EE      600000   // directed edges
#define GG      8192     // graphs
#define DIN     64       // input dim
#define HD      128      // hidden dim
#define NL      4        // layers
#define LN_EPS  1e-5f

static constexpr int NB_SCAN = (NN + 255) / 256;   // 782 blocks for node scan

typedef __attribute__((ext_vector_type(8))) short short8;   // 8 bf16 (4 VGPRs)
typedef __attribute__((ext_vector_type(4))) float floatx4;  // MFMA accumulator

// bf16x2 <-> float2 (exact: bf16->f32 is a 16-bit shift)
__device__ inline float2 unpack_bf2(unsigned int p) {
    return make_float2(__uint_as_float(p << 16), __uint_as_float(p & 0xffff0000u));
}
__device__ inline unsigned int pack_bf2(float a, float b) {
    __hip_bfloat16 lo = __float2bfloat16(a);
    __hip_bfloat16 hi = __float2bfloat16(b);
    unsigned short ul = *reinterpret_cast<unsigned short*>(&lo);
    unsigned short uh = *reinterpret_cast<unsigned short*>(&hi);
    return (unsigned int)ul | ((unsigned int)uh << 16);
}
__device__ inline short bf16bits(float x) {
    __hip_bfloat16 t = __float2bfloat16(x);
    return *reinterpret_cast<short*>(&t);
}
__device__ inline float silu(float v) { return v / (1.f + __expf(-v)); }

// fragment-layout index for W[c][k] with inner dim K:
// slot = ((k/32)*8 + c/16)*64 + ((k>>3)&3)*16 + (c&15), elem j = k&7
__device__ __host__ inline size_t fragidx(int c, int k) {
    return (size_t)((((k >> 5) * 8 + (c >> 4)) * 64 + ((k >> 3) & 3) * 16 + (c & 15)) * 8
                    + (k & 7));
}

// ---------------------------------------------------------------------------
// CSR build: degree histogram -> exclusive scan (+dis) -> edge fill
// ---------------------------------------------------------------------------
__global__ void hist_kernel(const int* __restrict__ dst, int* __restrict__ degi) {
    int e = blockIdx.x * 256 + threadIdx.x;
    if (e < EE) atomicAdd(&degi[dst[e]], 1);
}

__global__ void scan1_kernel(const int* __restrict__ degi, int* __restrict__ offs,
                             int* __restrict__ bsums, float* __restrict__ dis) {
    __shared__ int s[256];
    int t = threadIdx.x;
    int i = blockIdx.x * 256 + t;
    int v = (i < NN) ? degi[i] : 0;
    if (i < NN) dis[i] = rsqrtf((float)v + 1.0f);   // folded dis computation
    s[t] = v;
    __syncthreads();
    for (int d = 1; d < 256; d <<= 1) {
        int add = (t >= d) ? s[t - d] : 0;
        __syncthreads();
        s[t] += add;
        __syncthreads();
    }
    if (i < NN) offs[i] = s[t] - v;
    if (t == 255) bsums[blockIdx.x] = s[255];
}

__global__ void scan2_kernel(int* __restrict__ bsums) {
    __shared__ int s[1024];
    int t = threadIdx.x;
    int v = (t < NB_SCAN) ? bsums[t] : 0;
    s[t] = v;
    __syncthreads();
    for (int d = 1; d < 1024; d <<= 1) {
        int add = (t >= d) ? s[t - d] : 0;
        __syncthreads();
        s[t] += add;
        __syncthreads();
    }
    if (t < NB_SCAN) bsums[t] = s[t] - v;
}

__global__ void scan3_kernel(int* __restrict__ offs, const int* __restrict__ bsums,
                             int* __restrict__ cursor) {
    int i = blockIdx.x * 256 + threadIdx.x;
    if (i < NN) {
        int v = offs[i] + bsums[blockIdx.x];
        offs[i]   = v;
        cursor[i] = v;
    } else if (i == NN) {
        offs[i] = EE;
    }
}

// csre[p] = {src, dis[src]*dis[dst]} -- per-edge norm precomputed
__global__ void fill_kernel(const int* __restrict__ src, const int* __restrict__ dst,
                            const float* __restrict__ dis,
                            int* __restrict__ cursor, int2* __restrict__ csre) {
    int e = blockIdx.x * 256 + threadIdx.x;
    if (e < EE) {
        int s = src[e], d = dst[e];
        int p = atomicAdd(&cursor[d], 1);
        csre[p] = make_int2(s, __float_as_int(dis[s] * dis[d]));
    }
}

// ---------------------------------------------------------------------------
// Weight conversion f32 -> bf16 FRAGMENT layout.
// ---------------------------------------------------------------------------
__global__ void cvtf_kernel(const float* __restrict__ src, __hip_bfloat16* __restrict__ dst,
                            int K, int sstride, int total) {
    int idx = blockIdx.x * 256 + threadIdx.x;
    if (idx >= total) return;
    int cg = idx / K;              // global out-col index (incl. matrix)
    int k  = idx - cg * K;
    int mat = cg >> 7;
    int c   = cg & 127;
    float v = src[(size_t)cg * sstride + k];
    dst[(size_t)mat * 128 * K + fragidx(c, k)] = __float2bfloat16(v);
}

// ---------------------------------------------------------------------------
// Fused tail weight (fragment layout, K=256): wf(c, 0:128) = W1a[c][:],
// wf(c, 128:256) = (W1a @ phys_w2)[c][:], biasf[c] = dot(W1a[c], phys_b2).
// ---------------------------------------------------------------------------
__global__ __launch_bounds__(128)
void pm_kernel(const float* __restrict__ head_w1, const float* __restrict__ phys_w2,
               const float* __restrict__ phys_b2, __hip_bfloat16* __restrict__ wf,
               float* __restrict__ biasf)
{
    int i = blockIdx.x;            // out col c
    int j = threadIdx.x;           // 0..127
    const float* w1a = head_w1 + (size_t)i * 256;
    wf[fragidx(i, j)] = __float2bfloat16(w1a[j]);
    float m = 0.f;
    #pragma unroll 4
    for (int c = 0; c < 128; ++c) m += w1a[c] * phys_w2[(size_t)c * 128 + j];
    wf[fragidx(i, 128 + j)] = __float2bfloat16(m);

    float t = w1a[j] * phys_b2[j];
    #pragma unroll
    for (int o = 32; o > 0; o >>= 1) t += __shfl_down(t, o);
    __shared__ float red[2];
    if ((j & 63) == 0) red[j >> 6] = t;
    __syncthreads();
    if (j == 0) biasf[i] = red[0] + red[1];
}

// ---------------------------------------------------------------------------
// Simple MFMA GEMM, zero LDS, W in fragment layout (coalesced L2-hot loads).
// C[M,128] = act(A[M,K] @ W^T (+bias)). 4 waves x (32 rows x 128 cols).
// Used for input projection (K=64, f32 A) and per-graph embp (K=128).
// ---------------------------------------------------------------------------
template<int K, bool AF32, bool BIAS, bool SILU_, bool WF32, bool WBF>
__global__ __launch_bounds__(256, 4)
void mgemm5(const void* __restrict__ Avp, const __hip_bfloat16* __restrict__ wfrag,
            const float* __restrict__ bias,
            float* __restrict__ Cf, __hip_bfloat16* __restrict__ Cb, int M)
{
    const int tid  = threadIdx.x;
    const int wave = tid >> 6;
    const int lane = tid & 63;
    const int l15  = lane & 15;
    const int quad = lane >> 4;
    const int m0   = blockIdx.x * 128;

    int ridx0 = m0 + wave * 32 + l15;
    int ridx1 = ridx0 + 16;
    if (ridx0 >= M) ridx0 = M - 1;
    if (ridx1 >= M) ridx1 = M - 1;

    constexpr int NC = K / 32;
    short8 a0[NC], a1[NC];
    const __hip_bfloat16* Ab = (const __hip_bfloat16*)Avp;
    const float*          Af = (const float*)Avp;
    #pragma unroll
    for (int kc = 0; kc < NC; ++kc) {
        int ko = kc * 32 + quad * 8;
        if (AF32) {
            const float* p0 = Af + (size_t)ridx0 * K + ko;
            const float* p1 = Af + (size_t)ridx1 * K + ko;
            float4 x0 = *(const float4*)p0, x1 = *(const float4*)(p0 + 4);
            float4 y0 = *(const float4*)p1, y1 = *(const float4*)(p1 + 4);
            float xv[8] = {x0.x, x0.y, x0.z, x0.w, x1.x, x1.y, x1.z, x1.w};
            float yv[8] = {y0.x, y0.y, y0.z, y0.w, y1.x, y1.y, y1.z, y1.w};
            #pragma unroll
            for (int j = 0; j < 8; ++j) { a0[kc][j] = bf16bits(xv[j]); a1[kc][j] = bf16bits(yv[j]); }
        } else {
            a0[kc] = *(const short8*)(Ab + (size_t)ridx0 * K + ko);
            a1[kc] = *(const short8*)(Ab + (size_t)ridx1 * K + ko);
        }
    }

    floatx4 acc[2][8];
    #pragma unroll
    for (int mi = 0; mi < 2; ++mi)
        #pragma unroll
        for (int ni = 0; ni < 8; ++ni) acc[mi][ni] = (floatx4)0.f;

    const short* Wp = (const short*)wfrag;
    #pragma unroll
    for (int kc = 0; kc < NC; ++kc) {
        #pragma unroll
        for (int ni = 0; ni < 8; ++ni) {
            short8 b = *(const short8*)(Wp + (size_t)((kc * 8 + ni) * 64 + lane) * 8);
            acc[0][ni] = __builtin_amdgcn_mfma_f32_16x16x32_bf16(a0[kc], b, acc[0][ni], 0, 0, 0);
            acc[1][ni] = __builtin_amdgcn_mfma_f32_16x16x32_bf16(a1[kc], b, acc[1][ni], 0, 0, 0);
        }
    }

    float bv[8];
    #pragma unroll
    for (int ni = 0; ni < 8; ++ni) if (BIAS) bv[ni] = bias[ni * 16 + l15];

    #pragma unroll
    for (int mi = 0; mi < 2; ++mi) {
        #pragma unroll
        for (int r = 0; r < 4; ++r) {
            const int m = m0 + wave * 32 + mi * 16 + quad * 4 + r;
            if (m < M) {
                #pragma unroll
                for (int ni = 0; ni < 8; ++ni) {
                    int col = ni * 16 + l15;
                    float v = acc[mi][ni][r];
                    if (BIAS)  v += bv[ni];
                    if (SILU_) v = silu(v);
                    if (WF32)  Cf[(size_t)m * HD + col] = v;
                    if (WBF)   Cb[(size_t)m * HD + col] = __float2bfloat16(v);
                }
            }
        }
    }
}

// ---------------------------------------------------------------------------
// FUSED GCN layer, 64-node tile for occupancy (gather is latency-bound):
// phase 1: aggregate h_in rows into LDS (bf16, pitch 136 -> 2-way free);
// phase 2: MFMA agg @ conv_w^T (fragment-layout W from global, no staging);
// epilogue: h_out = h_in + LN(silu(acc + cb)). Ping-pong h buffers.
// LDS 17.4 KB, VGPR capped at 85 -> target 6 blocks/CU (24 waves).
// ---------------------------------------------------------------------------
__global__ __launch_bounds__(256, 6)
void conv_fused(const __hip_bfloat16* __restrict__ hin,
                const __hip_bfloat16* __restrict__ wfrag,
                const float* __restrict__ dis,
                const int* __restrict__ offs, const int2* __restrict__ csre,
                const float* __restrict__ cb, const float* __restrict__ lng,
                const float* __restrict__ lnb,
                __hip_bfloat16* __restrict__ hout, int M)
{
    __shared__ short As[64 * 136];          // 17408 B
    const int tid  = threadIdx.x;
    const int wave = tid >> 6;
    const int lane = tid & 63;
    const int l15  = lane & 15;
    const int quad = lane >> 4;
    const int m0   = blockIdx.x * 64;

    // ---- phase 1: aggregation into LDS (16 node streams x 4 iters) ----
    {
        const int l16 = tid & 15;           // feature chunk (8 bf16 = uint4)
        const int ns  = tid >> 4;           // node stream 0..15
        const uint4* h4 = (const uint4*)hin;
        #pragma unroll
        for (int it = 0; it < 4; ++it) {
            int nl = it * 16 + ns;          // local node 0..63
            int n  = m0 + nl;
            float acc[8];
            if (n < M) {
                float dn = dis[n];
                uint4 sp = h4[(size_t)n * 16 + l16];
                float s = dn * dn;
                float2 f0 = unpack_bf2(sp.x), f1 = unpack_bf2(sp.y);
                float2 f2 = unpack_bf2(sp.z), f3 = unpack_bf2(sp.w);
                acc[0] = f0.x * s; acc[1] = f0.y * s;
                acc[2] = f1.x * s; acc[3] = f1.y * s;
                acc[4] = f2.x * s; acc[5] = f2.y * s;
                acc[6] = f3.x * s; acc[7] = f3.y * s;
                int e  = offs[n];
                int e1 = offs[n + 1];
                for (; e + 2 <= e1; e += 2) {
                    int2 ea = csre[e];
                    int2 eb = csre[e + 1];
                    uint4 pa = h4[(size_t)ea.x * 16 + l16];
                    uint4 pb = h4[(size_t)eb.x * 16 + l16];
                    float wa = __int_as_float(ea.y);
                    float wb = __int_as_float(eb.y);
                    float2 A0 = unpack_bf2(pa.x), A1 = unpack_bf2(pa.y);
                    float2 A2 = unpack_bf2(pa.z), A3 = unpack_bf2(pa.w);
                    float2 B0 = unpack_bf2(pb.x), B1 = unpack_bf2(pb.y);
                    float2 B2 = unpack_bf2(pb.z), B3 = unpack_bf2(pb.w);
                    acc[0] += wa * A0.x + wb * B0.x; acc[1] += wa * A0.y + wb * B0.y;
                    acc[2] += wa * A1.x + wb * B1.x; acc[3] += wa * A1.y + wb * B1.y;
                    acc[4] += wa * A2.x + wb * B2.x; acc[5] += wa * A2.y + wb * B2.y;
                    acc[6] += wa * A3.x + wb * B3.x; acc[7] += wa * A3.y + wb * B3.y;
                }
                if (e < e1) {
                    int2 ea = csre[e];
                    uint4 pa = h4[(size_t)ea.x * 16 + l16];
                    float wa = __int_as_float(ea.y);
                    float2 A0 = unpack_bf2(pa.x), A1 = unpack_bf2(pa.y);
                    float2 A2 = unpack_bf2(pa.z), A3 = unpack_bf2(pa.w);
                    acc[0] += wa * A0.x; acc[1] += wa * A0.y;
                    acc[2] += wa * A1.x; acc[3] += wa * A1.y;
                    acc[4] += wa * A2.x; acc[5] += wa * A2.y;
                    acc[6] += wa * A3.x; acc[7] += wa * A3.y;
                }
            } else {
                #pragma unroll
                for (int j = 0; j < 8; ++j) acc[j] = 0.f;
            }
            uint4 o;
            o.x = pack_bf2(acc[0], acc[1]);
            o.y = pack_bf2(acc[2], acc[3]);
            o.z = pack_bf2(acc[4], acc[5]);
            o.w = pack_bf2(acc[6], acc[7]);
            *(uint4*)&As[nl * 136 + l16 * 8] = o;
        }
    }
    __syncthreads();

    // ---- phase 2: each wave = 16 rows x 128 cols (1 row-block x 8 col-blocks) ----
    floatx4 acc[8];
    #pragma unroll
    for (int ni = 0; ni < 8; ++ni) acc[ni] = (floatx4)0.f;

    const short* Wp = (const short*)wfrag;
    #pragma unroll
    for (int kc = 0; kc < 4; ++kc) {
        int ko = kc * 32 + quad * 8;
        short8 fa = *(const short8*)&As[(wave * 16 + l15) * 136 + ko];
        #pragma unroll
        for (int ni = 0; ni < 8; ++ni) {
            short8 b = *(const short8*)(Wp + (size_t)((kc * 8 + ni) * 64 + lane) * 8);
            acc[ni] = __builtin_amdgcn_mfma_f32_16x16x32_bf16(fa, b, acc[ni], 0, 0, 0);
        }
    }

    // ---- epilogue: SiLU + LN + residual (read hin, write hout) ----
    float bv[8], gv[8], lbv[8];
    #pragma unroll
    for (int ni = 0; ni < 8; ++ni) {
        int col = ni * 16 + l15;
        bv[ni]  = cb[col];
        gv[ni]  = lng[col];
        lbv[ni] = lnb[col];
    }
    #pragma unroll
    for (int r = 0; r < 4; ++r) {
        const int m = m0 + wave * 16 + quad * 4 + r;
        float sv[8], p1 = 0.f, p2 = 0.f;
        #pragma unroll
        for (int ni = 0; ni < 8; ++ni) {
            float v = silu(acc[ni][r] + bv[ni]);
            sv[ni] = v; p1 += v; p2 += v * v;
        }
        #pragma unroll
        for (int o = 1; o < 16; o <<= 1) {
            p1 += __shfl_xor(p1, o);
            p2 += __shfl_xor(p2, o);
        }
        float mu  = p1 * (1.f / 128.f);
        float var = p2 * (1.f / 128.f) - mu * mu;
        float rs  = rsqrtf(var + LN_EPS);
        if (m < M) {
            #pragma unroll
            for (int ni = 0; ni < 8; ++ni) {
                int col = ni * 16 + l15;
                float y  = (sv[ni] - mu) * rs * gv[ni] + lbv[ni];
                float hn = __bfloat162float(hin[(size_t)m * HD + col]) + y;
                hout[(size_t)m * HD + col] = __float2bfloat16(hn);
            }
        }
    }
}

// ---------------------------------------------------------------------------
// FUSED tail, 64-row tile: phase 1: t1 = silu(h @ w_p1^T + b1) into LDS
// (h frags kept in regs); phase 2: t2 = [h | t1] @ wf^T + biasf;
// epilogue: out = dot(silu(t2 + embp[batch]), w2) + b2.
// ---------------------------------------------------------------------------
__global__ __launch_bounds__(256, 6)
void tail_fused(const __hip_bfloat16* __restrict__ hbf,
                const __hip_bfloat16* __restrict__ wp1f, const float* __restrict__ pb1,
                const __hip_bfloat16* __restrict__ wff,  const float* __restrict__ biasf,
                const float* __restrict__ embp, const int* __restrict__ bv,
                const float* __restrict__ w2, const float* __restrict__ b2,
                float* __restrict__ out, int M)
{
    __shared__ short T1[64 * 136];
    const int tid  = threadIdx.x;
    const int wave = tid >> 6;
    const int lane = tid & 63;
    const int l15  = lane & 15;
    const int quad = lane >> 4;
    const int m0   = blockIdx.x * 64;

    int ridx0 = m0 + wave * 16 + l15;
    if (ridx0 >= M) ridx0 = M - 1;

    // h fragments (kept for phase 2)
    short8 ah[4];
    #pragma unroll
    for (int kc = 0; kc < 4; ++kc)
        ah[kc] = *(const short8*)(hbf + (size_t)ridx0 * HD + kc * 32 + quad * 8);

    // ---- phase 1: t1 tile ----
    {
        floatx4 a1[8];
        #pragma unroll
        for (int ni = 0; ni < 8; ++ni) a1[ni] = (floatx4)0.f;
        const short* Wp = (const short*)wp1f;
        #pragma unroll
        for (int kc = 0; kc < 4; ++kc) {
            #pragma unroll
            for (int ni = 0; ni < 8; ++ni) {
                short8 b = *(const short8*)(Wp + (size_t)((kc * 8 + ni) * 64 + lane) * 8);
                a1[ni] = __builtin_amdgcn_mfma_f32_16x16x32_bf16(ah[kc], b, a1[ni], 0, 0, 0);
            }
        }
        float pbv[8];
        #pragma unroll
        for (int ni = 0; ni < 8; ++ni) pbv[ni] = pb1[ni * 16 + l15];
        #pragma unroll
        for (int r = 0; r < 4; ++r) {
            int ml = wave * 16 + quad * 4 + r;   // local row
            #pragma unroll
            for (int ni = 0; ni < 8; ++ni) {
                float v = silu(a1[ni][r] + pbv[ni]);
                T1[ml * 136 + ni * 16 + l15] = bf16bits(v);
            }
        }
    }
    __syncthreads();

    // ---- phase 2: t2 = [h | t1] @ wf^T ----
    floatx4 acc[8];
    #pragma unroll
    for (int ni = 0; ni < 8; ++ni) acc[ni] = (floatx4)0.f;

    const short* Wf = (const short*)wff;
    #pragma unroll
    for (int kc = 0; kc < 4; ++kc) {              // k = 0..127 : h part (regs)
        #pragma unroll
        for (int ni = 0; ni < 8; ++ni) {
            short8 b = *(const short8*)(Wf + (size_t)((kc * 8 + ni) * 64 + lane) * 8);
            acc[ni] = __builtin_amdgcn_mfma_f32_16x16x32_bf16(ah[kc], b, acc[ni], 0, 0, 0);
        }
    }
    #pragma unroll
    for (int kc = 4; kc < 8; ++kc) {              // k = 128..255 : t1 part (LDS)
        int ko = (kc - 4) * 32 + quad * 8;
        short8 ta = *(const short8*)&T1[(wave * 16 + l15) * 136 + ko];
        #pragma unroll
        for (int ni = 0; ni < 8; ++ni) {
            short8 b = *(const short8*)(Wf + (size_t)((kc * 8 + ni) * 64 + lane) * 8);
            acc[ni] = __builtin_amdgcn_mfma_f32_16x16x32_bf16(ta, b, acc[ni], 0, 0, 0);
        }
    }

    // ---- epilogue: silu(t2 + embp[batch]) . w2 + b2 -> out ----
    float bfv[8], w2v[8];
    #pragma unroll
    for (int ni = 0; ni < 8; ++ni) {
        int col = ni * 16 + l15;
        bfv[ni] = biasf[col];
        w2v[ni] = w2[col];
    }
    const float b2v = b2[0];
    #pragma unroll
    for (int r = 0; r < 4; ++r) {
        const int m = m0 + wave * 16 + quad * 4 + r;
        if (m >= M) continue;
        int g = bv[m];
        float p = 0.f;
        #pragma unroll
        for (int ni = 0; ni < 8; ++ni) {
            int col = ni * 16 + l15;
            float v = acc[ni][r] + bfv[ni] + embp[(size_t)g * HD + col];
            p += silu(v) * w2v[ni];
        }
        #pragma unroll
        for (int o = 1; o < 16; o <<= 1) p += __shfl_xor(p, o);
        if (l15 == 0) out[m] = p + b2v;
    }
}

// ---------------------------------------------------------------------------
// Graph pooling: offsets via binary search (batch_vec sorted), mean -> bf16.
// ---------------------------------------------------------------------------
__global__ void goff_kernel(const int* __restrict__ bv, int* __restrict__ goff) {
    int g = blockIdx.x * 256 + threadIdx.x;
    if (g > GG) return;
    int lo = 0, hi = NN;
    while (lo < hi) {
        int mid = (lo + hi) >> 1;
        if (bv[mid] < g) lo = mid + 1; else hi = mid;
    }
    goff[g] = lo;
}

__global__ __launch_bounds__(64)
void pool_kernel(const unsigned int* __restrict__ hu, const int* __restrict__ goff,
                 unsigned int* __restrict__ embu)
{
    int g = blockIdx.x;
    int f = threadIdx.x;          // 0..63
    int i0 = goff[g], i1 = goff[g + 1];
    float s0 = 0.f, s1 = 0.f;
    for (int i = i0; i < i1; ++i) {
        float2 v = unpack_bf2(hu[(size_t)i * 64 + f]);
        s0 += v.x; s1 += v.y;
    }
    float c = fmaxf((float)(i1 - i0), 1.f);
    embu[(size_t)g * 64 + f] = pack_bf2(s0 / c, s1 / c);
}

// ---------------------------------------------------------------------------
// Launcher
// ---------------------------------------------------------------------------
extern "C" void kernel_launch(void* const* d_in, const int* in_sizes, int n_in,
                              void* d_out, int out_size, void* d_ws, size_t ws_size,
                              hipStream_t stream)
{
    const float* x        = (const float*)d_in[0];
    const int*   eidx     = (const int*)d_in[1];
    const int*   batchv   = (const int*)d_in[2];
    const float* in_w     = (const float*)d_in[3];
    const float* in_b     = (const float*)d_in[4];
    const float* conv_w   = (const float*)d_in[5];
    const float* conv_b   = (const float*)d_in[6];
    const float* ln_g     = (const float*)d_in[7];
    const float* ln_b     = (const float*)d_in[8];
    const float* phys_w1  = (const float*)d_in[9];
    const float* phys_b1  = (const float*)d_in[10];
    const float* phys_w2  = (const float*)d_in[11];
    const float* phys_b2  = (const float*)d_in[12];
    const float* head_w1  = (const float*)d_in[13];
    const float* head_b1  = (const float*)d_in[14];
    const float* head_w2  = (const float*)d_in[15];
    const float* head_b2  = (const float*)d_in[16];
    float* out = (float*)d_out;

    const int* esrc = eidx;
    const int* edst = eidx + EE;

    // workspace layout (~130 MB)
    char* base = (char*)d_ws;
    size_t off = 0;
    auto alloc = [&](size_t bytes) {
        char* p = base + off;
        off = (off + bytes + 255) & ~(size_t)255;
        return p;
    };
    __hip_bfloat16* h0     = (__hip_bfloat16*)alloc((size_t)NN * HD * 2);
    __hip_bfloat16* h1     = (__hip_bfloat16*)alloc((size_t)NN * HD * 2);
    float*          dis    = (float*)alloc((size_t)NN * 4);
    int*            degi   = (int*)  alloc((size_t)NN * 4);
    int*            offs   = (int*)  alloc((size_t)(NN + 1) * 4);
    int*            cursor = (int*)  alloc((size_t)NN * 4);
    int2*           csre   = (int2*) alloc((size_t)EE * 8);
    __hip_bfloat16* emb    = (__hip_bfloat16*)alloc((size_t)GG * HD * 2);
    float*          embp   = (float*)alloc((size_t)GG * HD * 4);
    int*            goff   = (int*)  alloc((size_t)(GG + 1) * 4);
    int*            bsums  = (int*)  alloc(1024 * 4);
    __hip_bfloat16* w_in   = (__hip_bfloat16*)alloc(HD * DIN * 2);
    __hip_bfloat16* w_conv = (__hip_bfloat16*)alloc((size_t)NL * HD * HD * 2);
    __hip_bfloat16* w_p1   = (__hip_bfloat16*)alloc(HD * HD * 2);
    __hip_bfloat16* w_h1b  = (__hip_bfloat16*)alloc(HD * HD * 2);
    __hip_bfloat16* wf     = (__hip_bfloat16*)alloc(HD * 2 * HD * 2);
    float*          biasf  = (float*)alloc(HD * 4);
    (void)ws_size; (void)n_in; (void)in_sizes; (void)out_size;

    const int GB128 = (NN + 127) / 128;   // 1563 blocks (mgemm5)
    const int GB64  = (NN + 63) / 64;     // 3125 blocks (fused kernels)

    // --- weight prep: fragment layouts (tiny) ---
    cvtf_kernel<<<(HD * DIN + 255) / 256, 256, 0, stream>>>(in_w, w_in, DIN, DIN, HD * DIN);
    cvtf_kernel<<<(NL * HD * HD + 255) / 256, 256, 0, stream>>>(conv_w, w_conv, HD, HD, NL * HD * HD);
    cvtf_kernel<<<(HD * HD + 255) / 256, 256, 0, stream>>>(phys_w1, w_p1, HD, HD, HD * HD);
    cvtf_kernel<<<(HD * HD + 255) / 256, 256, 0, stream>>>(head_w1 + HD, w_h1b, HD, 2 * HD, HD * HD);
    pm_kernel<<<HD, HD, 0, stream>>>(head_w1, phys_w2, phys_b2, wf, biasf);

    // --- CSR build ---
    hipMemsetAsync(degi, 0, (size_t)NN * 4, stream);
    hist_kernel<<<(EE + 255) / 256, 256, 0, stream>>>(edst, degi);
    scan1_kernel<<<NB_SCAN, 256, 0, stream>>>(degi, offs, bsums, dis);
    scan2_kernel<<<1, 1024, 0, stream>>>(bsums);
    scan3_kernel<<<NB_SCAN, 256, 0, stream>>>(offs, bsums, cursor);
    fill_kernel<<<(EE + 255) / 256, 256, 0, stream>>>(esrc, edst, dis, cursor, csre);

    // --- input projection: h0 = x @ in_w^T + in_b ---
    mgemm5<DIN, true, true, false, false, true><<<GB128, 256, 0, stream>>>(
        x, w_in, in_b, nullptr, h0, NN);

    // --- GCN layers (fused agg + conv + SiLU + LN + residual, ping-pong) ---
    for (int l = 0; l < NL; ++l) {
        const __hip_bfloat16* hin  = (l & 1) ? h1 : h0;
        __hip_bfloat16*       hout = (l & 1) ? h0 : h1;
        conv_fused<<<GB64, 256, 0, stream>>>(
            hin, w_conv + (size_t)l * HD * HD, dis, offs, csre,
            conv_b + l * HD, ln_g + l * HD, ln_b + l * HD, hout, NN);
    }
    // after 4 layers final h is in h0

    // --- graph mean pooling + per-graph head projection ---
    goff_kernel<<<(GG + 256) / 256, 256, 0, stream>>>(batchv, goff);
    pool_kernel<<<GG, 64, 0, stream>>>((const unsigned int*)h0, goff, (unsigned int*)emb);
    mgemm5<HD, false, true, false, true, false><<<GG / 128, 256, 0, stream>>>(
        emb, w_h1b, head_b1, embp, nullptr, GG);

    // --- fused phys MLP + head + output dot ---
    tail_fused<<<GB64, 256, 0, stream>>>(
        h0, w_p1, phys_b1, wf, biasf, embp, batchv, head_w2, head_b2, out, NN);
}